// Round 1
// baseline (1882.700 us; speedup 1.0000x reference)
//
#include <hip/hip_runtime.h>
#include <math.h>

#define DM   1024
#define LL   4096
#define NB   2
#define E3   3072
#define KDIM 1024

// ---------------------------------------------------------------------------
// K1: up[m][e] = sum_d u[m][d] * w_in[e][d] + b_in[e]
// A [8192][1024] row-major, W [3072][1024] row-major, C [8192][3072]
// 128x128 tile, BK=16, 256 threads, 8x8 microtile, LDS stored [k][m]
// ---------------------------------------------------------------------------
__global__ __launch_bounds__(256) void k_gemm_up(
    const float* __restrict__ A, const float* __restrict__ W,
    const float* __restrict__ bias, float* __restrict__ C)
{
    __shared__ float As[16][132];
    __shared__ float Bs[16][132];
    const int tid = threadIdx.x;
    const int tx = tid & 15, ty = tid >> 4;
    const int m0 = blockIdx.y * 128;
    const int n0 = blockIdx.x * 128;

    float acc[8][8];
#pragma unroll
    for (int i = 0; i < 8; ++i)
#pragma unroll
        for (int j = 0; j < 8; ++j) acc[i][j] = 0.f;

    for (int k0 = 0; k0 < KDIM; k0 += 16) {
#pragma unroll
        for (int p = 0; p < 2; ++p) {
            int fidx = p * 256 + tid;
            int row = fidx >> 2, kq = fidx & 3;
            float4 av = *reinterpret_cast<const float4*>(
                A + (size_t)(m0 + row) * KDIM + k0 + 4 * kq);
            As[4*kq+0][row] = av.x; As[4*kq+1][row] = av.y;
            As[4*kq+2][row] = av.z; As[4*kq+3][row] = av.w;
            float4 bv = *reinterpret_cast<const float4*>(
                W + (size_t)(n0 + row) * KDIM + k0 + 4 * kq);
            Bs[4*kq+0][row] = bv.x; Bs[4*kq+1][row] = bv.y;
            Bs[4*kq+2][row] = bv.z; Bs[4*kq+3][row] = bv.w;
        }
        __syncthreads();
#pragma unroll
        for (int kk = 0; kk < 16; ++kk) {
            float a[8], b[8];
            *reinterpret_cast<float4*>(&a[0]) = *reinterpret_cast<const float4*>(&As[kk][8*ty]);
            *reinterpret_cast<float4*>(&a[4]) = *reinterpret_cast<const float4*>(&As[kk][8*ty+4]);
            *reinterpret_cast<float4*>(&b[0]) = *reinterpret_cast<const float4*>(&Bs[kk][8*tx]);
            *reinterpret_cast<float4*>(&b[4]) = *reinterpret_cast<const float4*>(&Bs[kk][8*tx+4]);
#pragma unroll
            for (int i = 0; i < 8; ++i)
#pragma unroll
                for (int j = 0; j < 8; ++j) acc[i][j] = fmaf(a[i], b[j], acc[i][j]);
        }
        __syncthreads();
    }
    float bz[8];
#pragma unroll
    for (int j = 0; j < 8; ++j) bz[j] = bias[n0 + 8*tx + j];
#pragma unroll
    for (int i = 0; i < 8; ++i) {
        int row = m0 + 8 * ty + i;
        float* cp = C + (size_t)row * E3 + n0 + 8 * tx;
        float4 o0, o1;
        o0.x = acc[i][0] + bz[0]; o0.y = acc[i][1] + bz[1];
        o0.z = acc[i][2] + bz[2]; o0.w = acc[i][3] + bz[3];
        o1.x = acc[i][4] + bz[4]; o1.y = acc[i][5] + bz[5];
        o1.z = acc[i][6] + bz[6]; o1.w = acc[i][7] + bz[7];
        *reinterpret_cast<float4*>(cp)     = o0;
        *reinterpret_cast<float4*>(cp + 4) = o1;
    }
}

// ---------------------------------------------------------------------------
// K2: depthwise conv3 (causal: w0*x[t-2]+w1*x[t-1]+w2*x[t]+b), split into
// x0 / x1 / v, gate vin = v*x1, and write x0t, vin TRANSPOSED [b][c][t].
// Block: 32 channels x 64 t; grid (32, 64, 2)
// ---------------------------------------------------------------------------
__global__ __launch_bounds__(256) void k_dwconv(
    const float* __restrict__ up, const float* __restrict__ sfw,
    const float* __restrict__ sfb, float* __restrict__ x0t,
    float* __restrict__ vin)
{
    __shared__ float xT[32][65];
    __shared__ float vT[32][65];
    const int b  = blockIdx.z;
    const int t0 = blockIdx.y * 64;
    const int c0 = blockIdx.x * 32;
    const int tid = threadIdx.x;
    const int cL = tid & 31, tL = tid >> 5;   // tL 0..7
    const float* upb = up + (size_t)b * LL * E3;
    const int c = c0 + cL;

#pragma unroll
    for (int r = 0; r < 8; ++r) {
        int t_local = (r << 3) + tL;
        int t = t0 + t_local;
        float res[3];
#pragma unroll
        for (int s3 = 0; s3 < 3; ++s3) {
            int e = c + (s3 << 10);
            float w0 = sfw[e*3+0], w1 = sfw[e*3+1], w2 = sfw[e*3+2];
            float xa = (t >= 2) ? upb[(size_t)(t-2)*E3 + e] : 0.f;
            float xb = (t >= 1) ? upb[(size_t)(t-1)*E3 + e] : 0.f;
            float xc = upb[(size_t)t*E3 + e];
            res[s3] = w0*xa + w1*xb + w2*xc + sfb[e];
        }
        xT[cL][t_local] = res[0];
        vT[cL][t_local] = res[1] * res[2];
    }
    __syncthreads();
    const int cW = tid >> 3, q = tid & 7;
    float tmp[8];
#pragma unroll
    for (int i = 0; i < 8; ++i) tmp[i] = xT[cW][8*q + i];
    size_t off = ((size_t)b * DM + c0 + cW) * LL + t0 + 8*q;
    *reinterpret_cast<float4*>(x0t + off)     = make_float4(tmp[0], tmp[1], tmp[2], tmp[3]);
    *reinterpret_cast<float4*>(x0t + off + 4) = make_float4(tmp[4], tmp[5], tmp[6], tmp[7]);
#pragma unroll
    for (int i = 0; i < 8; ++i) tmp[i] = vT[cW][8*q + i];
    *reinterpret_cast<float4*>(vin + off)     = make_float4(tmp[0], tmp[1], tmp[2], tmp[3]);
    *reinterpret_cast<float4*>(vin + off + 4) = make_float4(tmp[4], tmp[5], tmp[6], tmp[7]);
}

// ---------------------------------------------------------------------------
// K3a: filter MLP  H3[t][j] = sin-MLP(z[t])
// grid 64 blocks (64 t each), 256 threads: (tl = tid>>6 in 0..3, j = tid&63)
// ---------------------------------------------------------------------------
__global__ __launch_bounds__(256) void k_filt_mlp(
    const float* __restrict__ z, const float* __restrict__ w0,
    const float* __restrict__ b0, const float* __restrict__ fr,
    const float* __restrict__ w1, const float* __restrict__ b1,
    const float* __restrict__ w2, const float* __restrict__ b2,
    float* __restrict__ H3)
{
    __shared__ float w1t[64 * 65];   // [m][j] padded
    __shared__ float w2t[64 * 65];
    __shared__ float hb[4][64];
    const int tid = threadIdx.x;
    for (int idx = tid; idx < 4096; idx += 256) {
        int j = idx >> 6, m = idx & 63;
        w1t[m*65 + j] = w1[idx];
        w2t[m*65 + j] = w2[idx];
    }
    __syncthreads();
    const int tl = tid >> 6, j = tid & 63;
    const float frj = fr[j];
    const float b0j = b0[j], b1j = b1[j], b2j = b2[j];
    const float w00 = w0[j*3+0], w01 = w0[j*3+1], w02 = w0[j*3+2];
    const int t0 = blockIdx.x * 64;
    for (int r = 0; r < 16; ++r) {
        int t = t0 + r*4 + tl;
        float z0 = z[t*3+0], z1 = z[t*3+1], z2 = z[t*3+2];
        float h = sinf(frj * (b0j + z0*w00 + z1*w01 + z2*w02));
        hb[tl][j] = h;
        __syncthreads();
        float s = b1j;
#pragma unroll
        for (int m = 0; m < 64; ++m) s = fmaf(hb[tl][m], w1t[m*65 + j], s);
        __syncthreads();
        h = sinf(frj * s);
        hb[tl][j] = h;
        __syncthreads();
        s = b2j;
#pragma unroll
        for (int m = 0; m < 64; ++m) s = fmaf(hb[tl][m], w2t[m*65 + j], s);
        h = sinf(frj * s);
        H3[(size_t)t * 64 + j] = h;
        __syncthreads();
    }
}

// ---------------------------------------------------------------------------
// K3b: kf[d][t] = (sum_j H3[t][j]*wf[d][j]) * exp(-tn*|delta_d|)
// grid (64 t-tiles, 16 d-tiles), 64x64 tile, 4x4 microtile
// ---------------------------------------------------------------------------
__global__ __launch_bounds__(256) void k_filt_k(
    const float* __restrict__ H3, const float* __restrict__ wf,
    float* __restrict__ kf)
{
    __shared__ float Hs[64][65];   // [t][j]
    __shared__ float Ws[64][65];   // [d][j]
    const int tid = threadIdx.x;
    const int t0 = blockIdx.x * 64, d0 = blockIdx.y * 64;
    for (int idx = tid; idx < 4096; idx += 256) {
        int r = idx >> 6, cc = idx & 63;
        Hs[r][cc] = H3[(size_t)(t0 + r) * 64 + cc];
        Ws[r][cc] = wf[(size_t)(d0 + r) * 64 + cc];
    }
    __syncthreads();
    const int tx = tid & 15, ty = tid >> 4;
    float acc[4][4];
#pragma unroll
    for (int i = 0; i < 4; ++i)
#pragma unroll
        for (int jj = 0; jj < 4; ++jj) acc[i][jj] = 0.f;
#pragma unroll
    for (int j = 0; j < 64; ++j) {
        float wv[4], hv[4];
#pragma unroll
        for (int i = 0; i < 4; ++i) wv[i] = Ws[4*ty + i][j];
#pragma unroll
        for (int i = 0; i < 4; ++i) hv[i] = Hs[4*tx + i][j];
#pragma unroll
        for (int i = 0; i < 4; ++i)
#pragma unroll
            for (int jj = 0; jj < 4; ++jj) acc[i][jj] = fmaf(wv[i], hv[jj], acc[i][jj]);
    }
    const float mind = -3.0701134573253944f;   // log(0.01)/1.5
    const float maxd = -15.350567286626972f;   // log(0.01)/0.3
#pragma unroll
    for (int i = 0; i < 4; ++i) {
        int d = d0 + 4*ty + i;
        float delta = fabsf(mind + (maxd - mind) * ((float)d / 1023.f));
#pragma unroll
        for (int jj = 0; jj < 4; ++jj) {
            int t = t0 + 4*tx + jj;
            float tn = (float)t / 4095.f;
            kf[(size_t)d * LL + t] = acc[i][jj] * expf(-tn * delta);
        }
    }
}

// ---------------------------------------------------------------------------
// K4: causal conv per (b,d): y[t] = sum_{s<=t} v[s]*k[t-s] + D[d]*v[t]
// One block per (d,b), 512 threads, 8 consecutive t per thread,
// sliding register window over k (LDS, 1/8-padded to break bank conflicts)
// ---------------------------------------------------------------------------
__global__ __launch_bounds__(512) void k_conv(
    const float* __restrict__ vin, const float* __restrict__ kf,
    const float* __restrict__ Dp, float* __restrict__ ytmp)
{
    __shared__ float vb[4096];
    __shared__ float kp[4608];
    const int d = blockIdx.x, b = blockIdx.y;
    const int tid = threadIdx.x;
    const float* vrow = vin + ((size_t)b * DM + d) * LL;
    const float* krow = kf + (size_t)d * LL;
    for (int i = tid; i < 1024; i += 512) {
        float4 v4 = reinterpret_cast<const float4*>(vrow)[i];
        reinterpret_cast<float4*>(vb)[i] = v4;
        float4 k4 = reinterpret_cast<const float4*>(krow)[i];
        int x = 4 * i;
        kp[x     + ( x      >> 3)] = k4.x;
        kp[x + 1 + ((x + 1) >> 3)] = k4.y;
        kp[x + 2 + ((x + 2) >> 3)] = k4.z;
        kp[x + 3 + ((x + 3) >> 3)] = k4.w;
    }
    __syncthreads();
    const int t0 = tid * 8;
    float kw[8], acc[8];
#pragma unroll
    for (int j = 0; j < 8; ++j) {
        int x = t0 + j;
        kw[j] = kp[x + (x >> 3)];
        acc[j] = 0.f;
    }
    const int smax = 8 * (tid | 63) + 8;   // wave-uniform triangle bound
#pragma unroll 8
    for (int s = 0; s < smax; ++s) {
        float vs = vb[s];
#pragma unroll
        for (int j = 0; j < 8; ++j) acc[j] = fmaf(vs, kw[j], acc[j]);
        int nx = t0 - s - 1;
        float nk = 0.f;
        if (nx >= 0) nk = kp[nx + (nx >> 3)];
#pragma unroll
        for (int j = 7; j > 0; --j) kw[j] = kw[j-1];
        kw[0] = nk;
    }
    const float Dd = Dp[d];
#pragma unroll
    for (int j = 0; j < 8; ++j) acc[j] = fmaf(Dd, vb[t0 + j], acc[j]);
    float* orow = ytmp + ((size_t)b * DM + d) * LL + t0;
    *reinterpret_cast<float4*>(orow)     = make_float4(acc[0], acc[1], acc[2], acc[3]);
    *reinterpret_cast<float4*>(orow + 4) = make_float4(acc[4], acc[5], acc[6], acc[7]);
}

// ---------------------------------------------------------------------------
// K5: out[m][n] = sum_d (ytmp[b][d][t]*x0t[b][d][t]) * w_out[n][d] + b_out[n]
// Same GEMM structure; A-tile gathered (coalesced along t) + gated on the fly
// ---------------------------------------------------------------------------
__global__ __launch_bounds__(256) void k_gemm_out(
    const float* __restrict__ Y, const float* __restrict__ X0,
    const float* __restrict__ W, const float* __restrict__ bias,
    float* __restrict__ C)
{
    __shared__ float As[16][132];
    __shared__ float Bs[16][132];
    const int tid = threadIdx.x;
    const int tx = tid & 15, ty = tid >> 4;
    const int m0 = blockIdx.y * 128;
    const int n0 = blockIdx.x * 128;
    const int b  = m0 >> 12;         // 4096 % 128 == 0: tile never straddles batch
    const int t0 = m0 & 4095;

    float acc[8][8];
#pragma unroll
    for (int i = 0; i < 8; ++i)
#pragma unroll
        for (int j = 0; j < 8; ++j) acc[i][j] = 0.f;

    for (int k0 = 0; k0 < KDIM; k0 += 16) {
#pragma unroll
        for (int p = 0; p < 8; ++p) {
            int idx = p * 256 + tid;            // 0..2047
            int trow = idx & 127, kcol = idx >> 7;
            size_t off = ((size_t)b * DM + (k0 + kcol)) * LL + t0 + trow;
            As[kcol][trow] = Y[off] * X0[off];
        }
#pragma unroll
        for (int p = 0; p < 2; ++p) {
            int fidx = p * 256 + tid;
            int row = fidx >> 2, kq = fidx & 3;
            float4 bv = *reinterpret_cast<const float4*>(
                W + (size_t)(n0 + row) * KDIM + k0 + 4 * kq);
            Bs[4*kq+0][row] = bv.x; Bs[4*kq+1][row] = bv.y;
            Bs[4*kq+2][row] = bv.z; Bs[4*kq+3][row] = bv.w;
        }
        __syncthreads();
#pragma unroll
        for (int kk = 0; kk < 16; ++kk) {
            float a[8], bb[8];
            *reinterpret_cast<float4*>(&a[0])  = *reinterpret_cast<const float4*>(&As[kk][8*ty]);
            *reinterpret_cast<float4*>(&a[4])  = *reinterpret_cast<const float4*>(&As[kk][8*ty+4]);
            *reinterpret_cast<float4*>(&bb[0]) = *reinterpret_cast<const float4*>(&Bs[kk][8*tx]);
            *reinterpret_cast<float4*>(&bb[4]) = *reinterpret_cast<const float4*>(&Bs[kk][8*tx+4]);
#pragma unroll
            for (int i = 0; i < 8; ++i)
#pragma unroll
                for (int j = 0; j < 8; ++j) acc[i][j] = fmaf(a[i], bb[j], acc[i][j]);
        }
        __syncthreads();
    }
    float bz[8];
#pragma unroll
    for (int j = 0; j < 8; ++j) bz[j] = bias[n0 + 8*tx + j];
#pragma unroll
    for (int i = 0; i < 8; ++i) {
        int row = m0 + 8 * ty + i;
        float* cp = C + (size_t)row * DM + n0 + 8 * tx;
        float4 o0, o1;
        o0.x = acc[i][0] + bz[0]; o0.y = acc[i][1] + bz[1];
        o0.z = acc[i][2] + bz[2]; o0.w = acc[i][3] + bz[3];
        o1.x = acc[i][4] + bz[4]; o1.y = acc[i][5] + bz[5];
        o1.z = acc[i][6] + bz[6]; o1.w = acc[i][7] + bz[7];
        *reinterpret_cast<float4*>(cp)     = o0;
        *reinterpret_cast<float4*>(cp + 4) = o1;
    }
}

// ---------------------------------------------------------------------------
extern "C" void kernel_launch(void* const* d_in, const int* in_sizes, int n_in,
                              void* d_out, int out_size, void* d_ws, size_t ws_size,
                              hipStream_t stream)
{
    if (n_in < 17) return;
    const float* u    = (const float*)d_in[0];
    const float* w_in = (const float*)d_in[1];
    const float* b_in = (const float*)d_in[2];
    const float* sf_w = (const float*)d_in[3];
    const float* sf_b = (const float*)d_in[4];
    const float* z    = (const float*)d_in[5];
    const float* w0   = (const float*)d_in[6];
    const float* b0   = (const float*)d_in[7];
    const float* freq = (const float*)d_in[8];
    const float* w1   = (const float*)d_in[9];
    const float* b1   = (const float*)d_in[10];
    const float* w2   = (const float*)d_in[11];
    const float* b2   = (const float*)d_in[12];
    const float* wf   = (const float*)d_in[13];
    const float* Dp   = (const float*)d_in[14];
    const float* wout = (const float*)d_in[15];
    const float* bout = (const float*)d_in[16];
    float* out = (float*)d_out;
    float* ws  = (float*)d_ws;

    // workspace layout (floats)
    const size_t UP_SZ  = (size_t)NB * LL * E3;      // 25,165,824
    const size_t BDL_SZ = (size_t)NB * DM * LL;      //  8,388,608
    const size_t KF_SZ  = (size_t)DM * LL;           //  4,194,304
    const size_t H3_SZ  = (size_t)LL * 64;           //    262,144
    float* up   = ws;
    float* x0t  = up + UP_SZ;
    float* vin  = x0t + BDL_SZ;
    float* kf   = vin + BDL_SZ;
    float* H3   = kf + KF_SZ;
    float* ytmp = H3 + H3_SZ;
    const size_t NEED = (UP_SZ + 3*BDL_SZ + KF_SZ + H3_SZ) * sizeof(float);
    if (ws_size < NEED) return;   // clean fail instead of corruption

    hipLaunchKernelGGL(k_gemm_up,  dim3(E3/128, 8192/128), dim3(256), 0, stream,
                       u, w_in, b_in, up);
    hipLaunchKernelGGL(k_dwconv,   dim3(DM/32, LL/64, NB), dim3(256), 0, stream,
                       up, sf_w, sf_b, x0t, vin);
    hipLaunchKernelGGL(k_filt_mlp, dim3(LL/64), dim3(256), 0, stream,
                       z, w0, b0, freq, w1, b1, w2, b2, H3);
    hipLaunchKernelGGL(k_filt_k,   dim3(LL/64, DM/64), dim3(256), 0, stream,
                       H3, wf, kf);
    hipLaunchKernelGGL(k_conv,     dim3(DM, NB), dim3(512), 0, stream,
                       vin, kf, Dp, ytmp);
    hipLaunchKernelGGL(k_gemm_out, dim3(DM/128, 8192/128), dim3(256), 0, stream,
                       ytmp, x0t, wout, bout, out);
}

// Round 2
// 1088.915 us; speedup vs baseline: 1.7290x; 1.7290x over previous
//
#include <hip/hip_runtime.h>
#include <math.h>

#define DM   1024
#define LL   4096
#define NB   2
#define E3   3072
#define KDIM 1024
#define FPI  3.14159265358979323846f

// ---------------------------------------------------------------------------
// K1: up[m][e] = sum_d u[m][d] * w_in[e][d] + b_in[e]
// ---------------------------------------------------------------------------
__global__ __launch_bounds__(256) void k_gemm_up(
    const float* __restrict__ A, const float* __restrict__ W,
    const float* __restrict__ bias, float* __restrict__ C)
{
    __shared__ float As[16][132];
    __shared__ float Bs[16][132];
    const int tid = threadIdx.x;
    const int tx = tid & 15, ty = tid >> 4;
    const int m0 = blockIdx.y * 128;
    const int n0 = blockIdx.x * 128;

    float acc[8][8];
#pragma unroll
    for (int i = 0; i < 8; ++i)
#pragma unroll
        for (int j = 0; j < 8; ++j) acc[i][j] = 0.f;

    for (int k0 = 0; k0 < KDIM; k0 += 16) {
#pragma unroll
        for (int p = 0; p < 2; ++p) {
            int fidx = p * 256 + tid;
            int row = fidx >> 2, kq = fidx & 3;
            float4 av = *reinterpret_cast<const float4*>(
                A + (size_t)(m0 + row) * KDIM + k0 + 4 * kq);
            As[4*kq+0][row] = av.x; As[4*kq+1][row] = av.y;
            As[4*kq+2][row] = av.z; As[4*kq+3][row] = av.w;
            float4 bv = *reinterpret_cast<const float4*>(
                W + (size_t)(n0 + row) * KDIM + k0 + 4 * kq);
            Bs[4*kq+0][row] = bv.x; Bs[4*kq+1][row] = bv.y;
            Bs[4*kq+2][row] = bv.z; Bs[4*kq+3][row] = bv.w;
        }
        __syncthreads();
#pragma unroll
        for (int kk = 0; kk < 16; ++kk) {
            float a[8], b[8];
            *reinterpret_cast<float4*>(&a[0]) = *reinterpret_cast<const float4*>(&As[kk][8*ty]);
            *reinterpret_cast<float4*>(&a[4]) = *reinterpret_cast<const float4*>(&As[kk][8*ty+4]);
            *reinterpret_cast<float4*>(&b[0]) = *reinterpret_cast<const float4*>(&Bs[kk][8*tx]);
            *reinterpret_cast<float4*>(&b[4]) = *reinterpret_cast<const float4*>(&Bs[kk][8*tx+4]);
#pragma unroll
            for (int i = 0; i < 8; ++i)
#pragma unroll
                for (int j = 0; j < 8; ++j) acc[i][j] = fmaf(a[i], b[j], acc[i][j]);
        }
        __syncthreads();
    }
    float bz[8];
#pragma unroll
    for (int j = 0; j < 8; ++j) bz[j] = bias[n0 + 8*tx + j];
#pragma unroll
    for (int i = 0; i < 8; ++i) {
        int row = m0 + 8 * ty + i;
        float* cp = C + (size_t)row * E3 + n0 + 8 * tx;
        float4 o0, o1;
        o0.x = acc[i][0] + bz[0]; o0.y = acc[i][1] + bz[1];
        o0.z = acc[i][2] + bz[2]; o0.w = acc[i][3] + bz[3];
        o1.x = acc[i][4] + bz[4]; o1.y = acc[i][5] + bz[5];
        o1.z = acc[i][6] + bz[6]; o1.w = acc[i][7] + bz[7];
        *reinterpret_cast<float4*>(cp)     = o0;
        *reinterpret_cast<float4*>(cp + 4) = o1;
    }
}

// ---------------------------------------------------------------------------
// K2: depthwise conv3 + split + gate + transpose to [b][c][t]
// ---------------------------------------------------------------------------
__global__ __launch_bounds__(256) void k_dwconv(
    const float* __restrict__ up, const float* __restrict__ sfw,
    const float* __restrict__ sfb, float* __restrict__ x0t,
    float* __restrict__ vin)
{
    __shared__ float xT[32][65];
    __shared__ float vT[32][65];
    const int b  = blockIdx.z;
    const int t0 = blockIdx.y * 64;
    const int c0 = blockIdx.x * 32;
    const int tid = threadIdx.x;
    const int cL = tid & 31, tL = tid >> 5;
    const float* upb = up + (size_t)b * LL * E3;
    const int c = c0 + cL;

#pragma unroll
    for (int r = 0; r < 8; ++r) {
        int t_local = (r << 3) + tL;
        int t = t0 + t_local;
        float res[3];
#pragma unroll
        for (int s3 = 0; s3 < 3; ++s3) {
            int e = c + (s3 << 10);
            float w0 = sfw[e*3+0], w1 = sfw[e*3+1], w2 = sfw[e*3+2];
            float xa = (t >= 2) ? upb[(size_t)(t-2)*E3 + e] : 0.f;
            float xb = (t >= 1) ? upb[(size_t)(t-1)*E3 + e] : 0.f;
            float xc = upb[(size_t)t*E3 + e];
            res[s3] = w0*xa + w1*xb + w2*xc + sfb[e];
        }
        xT[cL][t_local] = res[0];
        vT[cL][t_local] = res[1] * res[2];
    }
    __syncthreads();
    const int cW = tid >> 3, q = tid & 7;
    float tmp[8];
#pragma unroll
    for (int i = 0; i < 8; ++i) tmp[i] = xT[cW][8*q + i];
    size_t off = ((size_t)b * DM + c0 + cW) * LL + t0 + 8*q;
    *reinterpret_cast<float4*>(x0t + off)     = make_float4(tmp[0], tmp[1], tmp[2], tmp[3]);
    *reinterpret_cast<float4*>(x0t + off + 4) = make_float4(tmp[4], tmp[5], tmp[6], tmp[7]);
#pragma unroll
    for (int i = 0; i < 8; ++i) tmp[i] = vT[cW][8*q + i];
    *reinterpret_cast<float4*>(vin + off)     = make_float4(tmp[0], tmp[1], tmp[2], tmp[3]);
    *reinterpret_cast<float4*>(vin + off + 4) = make_float4(tmp[4], tmp[5], tmp[6], tmp[7]);
}

// ---------------------------------------------------------------------------
// K3a: filter MLP
// ---------------------------------------------------------------------------
__global__ __launch_bounds__(256) void k_filt_mlp(
    const float* __restrict__ z, const float* __restrict__ w0,
    const float* __restrict__ b0, const float* __restrict__ fr,
    const float* __restrict__ w1, const float* __restrict__ b1,
    const float* __restrict__ w2, const float* __restrict__ b2,
    float* __restrict__ H3)
{
    __shared__ float w1t[64 * 65];
    __shared__ float w2t[64 * 65];
    __shared__ float hb[4][64];
    const int tid = threadIdx.x;
    for (int idx = tid; idx < 4096; idx += 256) {
        int j = idx >> 6, m = idx & 63;
        w1t[m*65 + j] = w1[idx];
        w2t[m*65 + j] = w2[idx];
    }
    __syncthreads();
    const int tl = tid >> 6, j = tid & 63;
    const float frj = fr[j];
    const float b0j = b0[j], b1j = b1[j], b2j = b2[j];
    const float w00 = w0[j*3+0], w01 = w0[j*3+1], w02 = w0[j*3+2];
    const int t0 = blockIdx.x * 64;
    for (int r = 0; r < 16; ++r) {
        int t = t0 + r*4 + tl;
        float z0 = z[t*3+0], z1 = z[t*3+1], z2 = z[t*3+2];
        float h = sinf(frj * (b0j + z0*w00 + z1*w01 + z2*w02));
        hb[tl][j] = h;
        __syncthreads();
        float s = b1j;
#pragma unroll
        for (int m = 0; m < 64; ++m) s = fmaf(hb[tl][m], w1t[m*65 + j], s);
        __syncthreads();
        h = sinf(frj * s);
        hb[tl][j] = h;
        __syncthreads();
        s = b2j;
#pragma unroll
        for (int m = 0; m < 64; ++m) s = fmaf(hb[tl][m], w2t[m*65 + j], s);
        h = sinf(frj * s);
        H3[(size_t)t * 64 + j] = h;
        __syncthreads();
    }
}

// ---------------------------------------------------------------------------
// K3b: kf[d][t] = (H3 @ wf^T) * exp-decay
// ---------------------------------------------------------------------------
__global__ __launch_bounds__(256) void k_filt_k(
    const float* __restrict__ H3, const float* __restrict__ wf,
    float* __restrict__ kf)
{
    __shared__ float Hs[64][65];
    __shared__ float Ws[64][65];
    const int tid = threadIdx.x;
    const int t0 = blockIdx.x * 64, d0 = blockIdx.y * 64;
    for (int idx = tid; idx < 4096; idx += 256) {
        int r = idx >> 6, cc = idx & 63;
        Hs[r][cc] = H3[(size_t)(t0 + r) * 64 + cc];
        Ws[r][cc] = wf[(size_t)(d0 + r) * 64 + cc];
    }
    __syncthreads();
    const int tx = tid & 15, ty = tid >> 4;
    float acc[4][4];
#pragma unroll
    for (int i = 0; i < 4; ++i)
#pragma unroll
        for (int jj = 0; jj < 4; ++jj) acc[i][jj] = 0.f;
#pragma unroll
    for (int j = 0; j < 64; ++j) {
        float wv[4], hv[4];
#pragma unroll
        for (int i = 0; i < 4; ++i) wv[i] = Ws[4*ty + i][j];
#pragma unroll
        for (int i = 0; i < 4; ++i) hv[i] = Hs[4*tx + i][j];
#pragma unroll
        for (int i = 0; i < 4; ++i)
#pragma unroll
            for (int jj = 0; jj < 4; ++jj) acc[i][jj] = fmaf(wv[i], hv[jj], acc[i][jj]);
    }
    const float mind = -3.0701134573253944f;
    const float maxd = -15.350567286626972f;
#pragma unroll
    for (int i = 0; i < 4; ++i) {
        int d = d0 + 4*ty + i;
        float delta = fabsf(mind + (maxd - mind) * ((float)d / 1023.f));
#pragma unroll
        for (int jj = 0; jj < 4; ++jj) {
            int t = t0 + 4*tx + jj;
            float tn = (float)t / 4095.f;
            kf[(size_t)d * LL + t] = acc[i][jj] * expf(-tn * delta);
        }
    }
}

// ---------------------------------------------------------------------------
// FFT helpers: 8192-pt complex, radix-2, DIF fwd (natural->scrambled),
// DIT inv (scrambled->natural). LDS stages h=4096..16, reg stages h=8..1.
// LDS layout padded: float2 index p stored at p + (p>>4).
// ---------------------------------------------------------------------------
__device__ __forceinline__ int pidx(int p) { return p + (p >> 4); }

__device__ __forceinline__ float2 cmul(float2 a, float2 b) {
    return make_float2(a.x*b.x - a.y*b.y, a.x*b.y + a.y*b.x);
}

__device__ void fft_lds_fwd(float2* buf, int tid) {
    for (int h = 4096; h >= 16; h >>= 1) {
        float rinv = -FPI / (float)h;
        __syncthreads();
#pragma unroll
        for (int r = 0; r < 8; ++r) {
            int bf = (r << 9) + tid;
            int pos = bf & (h - 1);
            int i = 2 * bf - pos;
            float2 a = buf[pidx(i)];
            float2 b = buf[pidx(i + h)];
            float2 s = make_float2(a.x + b.x, a.y + b.y);
            float2 d = make_float2(a.x - b.x, a.y - b.y);
            float sn, cs;
            __sincosf(rinv * (float)pos, &sn, &cs);
            buf[pidx(i)]     = s;
            buf[pidx(i + h)] = make_float2(d.x*cs - d.y*sn, d.x*sn + d.y*cs);
        }
    }
    __syncthreads();
}

__device__ void fft_lds_inv(float2* buf, int tid) {
    for (int h = 16; h <= 4096; h <<= 1) {
        float rinv = FPI / (float)h;
        __syncthreads();
#pragma unroll
        for (int r = 0; r < 8; ++r) {
            int bf = (r << 9) + tid;
            int pos = bf & (h - 1);
            int i = 2 * bf - pos;
            float2 a = buf[pidx(i)];
            float2 b = buf[pidx(i + h)];
            float sn, cs;
            __sincosf(rinv * (float)pos, &sn, &cs);
            float2 bt = make_float2(b.x*cs - b.y*sn, b.x*sn + b.y*cs);
            buf[pidx(i)]     = make_float2(a.x + bt.x, a.y + bt.y);
            buf[pidx(i + h)] = make_float2(a.x - bt.x, a.y - bt.y);
        }
    }
    __syncthreads();
}

__device__ __forceinline__ void fft_reg_fwd(float2* c) {
    const float W16r[8] = {1.f, 0.92387953f, 0.70710678f, 0.38268343f,
                           0.f, -0.38268343f, -0.70710678f, -0.92387953f};
    const float W16i[8] = {0.f, -0.38268343f, -0.70710678f, -0.92387953f,
                           -1.f, -0.92387953f, -0.70710678f, -0.38268343f};
#pragma unroll
    for (int k = 0; k < 8; ++k) {
        float2 a = c[k], b = c[k+8];
        float2 d = make_float2(a.x - b.x, a.y - b.y);
        c[k]   = make_float2(a.x + b.x, a.y + b.y);
        c[k+8] = cmul(d, make_float2(W16r[k], W16i[k]));
    }
    const float W8r[4] = {1.f, 0.70710678f, 0.f, -0.70710678f};
    const float W8i[4] = {0.f, -0.70710678f, -1.f, -0.70710678f};
#pragma unroll
    for (int blk = 0; blk < 16; blk += 8)
#pragma unroll
        for (int k = 0; k < 4; ++k) {
            float2 a = c[blk+k], b = c[blk+k+4];
            float2 d = make_float2(a.x - b.x, a.y - b.y);
            c[blk+k]   = make_float2(a.x + b.x, a.y + b.y);
            c[blk+k+4] = cmul(d, make_float2(W8r[k], W8i[k]));
        }
#pragma unroll
    for (int blk = 0; blk < 16; blk += 4) {
        {   float2 a = c[blk], b = c[blk+2];
            c[blk]   = make_float2(a.x + b.x, a.y + b.y);
            c[blk+2] = make_float2(a.x - b.x, a.y - b.y); }
        {   float2 a = c[blk+1], b = c[blk+3];
            float2 d = make_float2(a.x - b.x, a.y - b.y);
            c[blk+1] = make_float2(a.x + b.x, a.y + b.y);
            c[blk+3] = make_float2(d.y, -d.x); }          // *(0,-1)
    }
#pragma unroll
    for (int blk = 0; blk < 16; blk += 2) {
        float2 a = c[blk], b = c[blk+1];
        c[blk]   = make_float2(a.x + b.x, a.y + b.y);
        c[blk+1] = make_float2(a.x - b.x, a.y - b.y);
    }
}

__device__ __forceinline__ void fft_reg_inv(float2* c) {
#pragma unroll
    for (int blk = 0; blk < 16; blk += 2) {
        float2 a = c[blk], b = c[blk+1];
        c[blk]   = make_float2(a.x + b.x, a.y + b.y);
        c[blk+1] = make_float2(a.x - b.x, a.y - b.y);
    }
#pragma unroll
    for (int blk = 0; blk < 16; blk += 4) {
        {   float2 a = c[blk], b = c[blk+2];
            c[blk]   = make_float2(a.x + b.x, a.y + b.y);
            c[blk+2] = make_float2(a.x - b.x, a.y - b.y); }
        {   float2 a = c[blk+1], b = c[blk+3];
            float2 bt = make_float2(-c[blk+3].y, c[blk+3].x);   // *(0,+1)
            bt = make_float2(-b.y, b.x);
            c[blk+1] = make_float2(a.x + bt.x, a.y + bt.y);
            c[blk+3] = make_float2(a.x - bt.x, a.y - bt.y); }
    }
    const float W8r[4] = {1.f, 0.70710678f, 0.f, -0.70710678f};
    const float W8i[4] = {0.f, 0.70710678f, 1.f, 0.70710678f};   // conj
#pragma unroll
    for (int blk = 0; blk < 16; blk += 8)
#pragma unroll
        for (int k = 0; k < 4; ++k) {
            float2 a = c[blk+k], b = c[blk+k+4];
            float2 bt = cmul(b, make_float2(W8r[k], W8i[k]));
            c[blk+k]   = make_float2(a.x + bt.x, a.y + bt.y);
            c[blk+k+4] = make_float2(a.x - bt.x, a.y - bt.y);
        }
    const float W16r[8] = {1.f, 0.92387953f, 0.70710678f, 0.38268343f,
                           0.f, -0.38268343f, -0.70710678f, -0.92387953f};
    const float W16i[8] = {0.f, 0.38268343f, 0.70710678f, 0.92387953f,
                           1.f, 0.92387953f, 0.70710678f, 0.38268343f};  // conj
#pragma unroll
    for (int k = 0; k < 8; ++k) {
        float2 a = c[k], b = c[k+8];
        float2 bt = cmul(b, make_float2(W16r[k], W16i[k]));
        c[k]   = make_float2(a.x + bt.x, a.y + bt.y);
        c[k+8] = make_float2(a.x - bt.x, a.y - bt.y);
    }
}

// ---------------------------------------------------------------------------
// K4a: per-channel kernel spectrum (scrambled order, pre-scaled by 1/8192)
// ---------------------------------------------------------------------------
__global__ __launch_bounds__(512) void k_kfft(
    const float* __restrict__ kf, float2* __restrict__ Kf)
{
    __shared__ float2 buf[8704];
    const int d = blockIdx.x, tid = threadIdx.x;
    const float* krow = kf + (size_t)d * LL;
    for (int i = tid; i < 1024; i += 512) {
        float4 k4 = reinterpret_cast<const float4*>(krow)[i];
        int p = 4 * i;
        buf[pidx(p+0)] = make_float2(k4.x, 0.f);
        buf[pidx(p+1)] = make_float2(k4.y, 0.f);
        buf[pidx(p+2)] = make_float2(k4.z, 0.f);
        buf[pidx(p+3)] = make_float2(k4.w, 0.f);
    }
    for (int p = 4096 + tid; p < 8192; p += 512)
        buf[pidx(p)] = make_float2(0.f, 0.f);
    fft_lds_fwd(buf, tid);
    float2 c[16];
    const int p0 = tid * 16;
#pragma unroll
    for (int j = 0; j < 16; ++j) c[j] = buf[pidx(p0 + j)];
    fft_reg_fwd(c);
    float2* outp = Kf + (size_t)d * 8192 + p0;
#pragma unroll
    for (int j = 0; j < 16; ++j)
        outp[j] = make_float2(c[j].x * (1.f/8192.f), c[j].y * (1.f/8192.f));
}

// ---------------------------------------------------------------------------
// K4b: y = irfft-style circular conv (fwd FFT, mult by Kf, inv FFT) + D*v
// ---------------------------------------------------------------------------
__global__ __launch_bounds__(512) void k_fftconv(
    const float* __restrict__ vin, const float2* __restrict__ Kf,
    const float* __restrict__ Dp, float* __restrict__ ytmp)
{
    __shared__ float2 buf[8704];
    const int d = blockIdx.x, b = blockIdx.y, tid = threadIdx.x;
    const float* vrow = vin + ((size_t)b * DM + d) * LL;
    for (int i = tid; i < 1024; i += 512) {
        float4 v4 = reinterpret_cast<const float4*>(vrow)[i];
        int p = 4 * i;
        buf[pidx(p+0)] = make_float2(v4.x, 0.f);
        buf[pidx(p+1)] = make_float2(v4.y, 0.f);
        buf[pidx(p+2)] = make_float2(v4.z, 0.f);
        buf[pidx(p+3)] = make_float2(v4.w, 0.f);
    }
    for (int p = 4096 + tid; p < 8192; p += 512)
        buf[pidx(p)] = make_float2(0.f, 0.f);
    fft_lds_fwd(buf, tid);
    float2 c[16];
    const int p0 = tid * 16;
#pragma unroll
    for (int j = 0; j < 16; ++j) c[j] = buf[pidx(p0 + j)];
    fft_reg_fwd(c);
    const float2* kfr = Kf + (size_t)d * 8192 + p0;
#pragma unroll
    for (int j = 0; j < 16; ++j) c[j] = cmul(c[j], kfr[j]);
    fft_reg_inv(c);
#pragma unroll
    for (int j = 0; j < 16; ++j) buf[pidx(p0 + j)] = c[j];
    fft_lds_inv(buf, tid);
    const float Dd = Dp[d];
    float* orow = ytmp + ((size_t)b * DM + d) * LL;
    for (int i = tid; i < 1024; i += 512) {
        float4 v4 = reinterpret_cast<const float4*>(vrow)[i];
        int p = 4 * i;
        float4 o;
        o.x = buf[pidx(p+0)].x + Dd * v4.x;
        o.y = buf[pidx(p+1)].x + Dd * v4.y;
        o.z = buf[pidx(p+2)].x + Dd * v4.z;
        o.w = buf[pidx(p+3)].x + Dd * v4.w;
        reinterpret_cast<float4*>(orow)[i] = o;
    }
}

// ---------------------------------------------------------------------------
// K5: out = ((y*x0)^T @ w_out^T) + b_out
// ---------------------------------------------------------------------------
__global__ __launch_bounds__(256) void k_gemm_out(
    const float* __restrict__ Y, const float* __restrict__ X0,
    const float* __restrict__ W, const float* __restrict__ bias,
    float* __restrict__ C)
{
    __shared__ float As[16][132];
    __shared__ float Bs[16][132];
    const int tid = threadIdx.x;
    const int tx = tid & 15, ty = tid >> 4;
    const int m0 = blockIdx.y * 128;
    const int n0 = blockIdx.x * 128;
    const int b  = m0 >> 12;
    const int t0 = m0 & 4095;

    float acc[8][8];
#pragma unroll
    for (int i = 0; i < 8; ++i)
#pragma unroll
        for (int j = 0; j < 8; ++j) acc[i][j] = 0.f;

    for (int k0 = 0; k0 < KDIM; k0 += 16) {
#pragma unroll
        for (int p = 0; p < 8; ++p) {
            int idx = p * 256 + tid;
            int trow = idx & 127, kcol = idx >> 7;
            size_t off = ((size_t)b * DM + (k0 + kcol)) * LL + t0 + trow;
            As[kcol][trow] = Y[off] * X0[off];
        }
#pragma unroll
        for (int p = 0; p < 2; ++p) {
            int fidx = p * 256 + tid;
            int row = fidx >> 2, kq = fidx & 3;
            float4 bv = *reinterpret_cast<const float4*>(
                W + (size_t)(n0 + row) * KDIM + k0 + 4 * kq);
            Bs[4*kq+0][row] = bv.x; Bs[4*kq+1][row] = bv.y;
            Bs[4*kq+2][row] = bv.z; Bs[4*kq+3][row] = bv.w;
        }
        __syncthreads();
#pragma unroll
        for (int kk = 0; kk < 16; ++kk) {
            float a[8], bb[8];
            *reinterpret_cast<float4*>(&a[0])  = *reinterpret_cast<const float4*>(&As[kk][8*ty]);
            *reinterpret_cast<float4*>(&a[4])  = *reinterpret_cast<const float4*>(&As[kk][8*ty+4]);
            *reinterpret_cast<float4*>(&bb[0]) = *reinterpret_cast<const float4*>(&Bs[kk][8*tx]);
            *reinterpret_cast<float4*>(&bb[4]) = *reinterpret_cast<const float4*>(&Bs[kk][8*tx+4]);
#pragma unroll
            for (int i = 0; i < 8; ++i)
#pragma unroll
                for (int j = 0; j < 8; ++j) acc[i][j] = fmaf(a[i], bb[j], acc[i][j]);
        }
        __syncthreads();
    }
    float bz[8];
#pragma unroll
    for (int j = 0; j < 8; ++j) bz[j] = bias[n0 + 8*tx + j];
#pragma unroll
    for (int i = 0; i < 8; ++i) {
        int row = m0 + 8 * ty + i;
        float* cp = C + (size_t)row * DM + n0 + 8 * tx;
        float4 o0, o1;
        o0.x = acc[i][0] + bz[0]; o0.y = acc[i][1] + bz[1];
        o0.z = acc[i][2] + bz[2]; o0.w = acc[i][3] + bz[3];
        o1.x = acc[i][4] + bz[4]; o1.y = acc[i][5] + bz[5];
        o1.z = acc[i][6] + bz[6]; o1.w = acc[i][7] + bz[7];
        *reinterpret_cast<float4*>(cp)     = o0;
        *reinterpret_cast<float4*>(cp + 4) = o1;
    }
}

// ---------------------------------------------------------------------------
extern "C" void kernel_launch(void* const* d_in, const int* in_sizes, int n_in,
                              void* d_out, int out_size, void* d_ws, size_t ws_size,
                              hipStream_t stream)
{
    if (n_in < 17) return;
    const float* u    = (const float*)d_in[0];
    const float* w_in = (const float*)d_in[1];
    const float* b_in = (const float*)d_in[2];
    const float* sf_w = (const float*)d_in[3];
    const float* sf_b = (const float*)d_in[4];
    const float* z    = (const float*)d_in[5];
    const float* w0   = (const float*)d_in[6];
    const float* b0   = (const float*)d_in[7];
    const float* freq = (const float*)d_in[8];
    const float* w1   = (const float*)d_in[9];
    const float* b1   = (const float*)d_in[10];
    const float* w2   = (const float*)d_in[11];
    const float* b2   = (const float*)d_in[12];
    const float* wf   = (const float*)d_in[13];
    const float* Dp   = (const float*)d_in[14];
    const float* wout = (const float*)d_in[15];
    const float* bout = (const float*)d_in[16];
    float* out = (float*)d_out;
    float* ws  = (float*)d_ws;

    // workspace layout (floats):
    //   [0, UP_SZ)            : up  (phase 1)  ->  Kf (16.78M) + ytmp (8.39M)
    //   [UP_SZ, +BDL_SZ)      : x0t
    //   [.., +BDL_SZ)         : vin
    //   [.., +KF_SZ)          : kf (time-domain kernel)
    //   [.., +H3_SZ)          : H3
    const size_t UP_SZ   = (size_t)NB * LL * E3;     // 25,165,824
    const size_t BDL_SZ  = (size_t)NB * DM * LL;     //  8,388,608
    const size_t KF_SZ   = (size_t)DM * LL;          //  4,194,304
    const size_t H3_SZ   = (size_t)LL * 64;          //    262,144
    const size_t KFFT_SZ = (size_t)DM * 8192 * 2;    // 16,777,216
    static_assert((size_t)NB * LL * E3 == (size_t)DM * 8192 * 2 + (size_t)NB * DM * LL,
                  "Kf+ytmp must overlay up exactly");
    float*  up   = ws;
    float2* Kf   = (float2*)ws;                // overlays dead `up`
    float*  ytmp = ws + KFFT_SZ;               // overlays dead `up` tail
    float*  x0t  = ws + UP_SZ;
    float*  vin  = x0t + BDL_SZ;
    float*  kf   = vin + BDL_SZ;
    float*  H3   = kf + KF_SZ;
    const size_t NEED = (UP_SZ + 2 * BDL_SZ + KF_SZ + H3_SZ) * sizeof(float);
    if (ws_size < NEED) return;

    hipLaunchKernelGGL(k_gemm_up,  dim3(E3/128, 8192/128), dim3(256), 0, stream,
                       u, w_in, b_in, up);
    hipLaunchKernelGGL(k_dwconv,   dim3(DM/32, LL/64, NB), dim3(256), 0, stream,
                       up, sf_w, sf_b, x0t, vin);
    hipLaunchKernelGGL(k_filt_mlp, dim3(LL/64), dim3(256), 0, stream,
                       z, w0, b0, freq, w1, b1, w2, b2, H3);
    hipLaunchKernelGGL(k_filt_k,   dim3(LL/64, DM/64), dim3(256), 0, stream,
                       H3, wf, kf);
    hipLaunchKernelGGL(k_kfft,     dim3(DM), dim3(512), 0, stream,
                       kf, Kf);
    hipLaunchKernelGGL(k_fftconv,  dim3(DM, NB), dim3(512), 0, stream,
                       vin, Kf, Dp, ytmp);
    hipLaunchKernelGGL(k_gemm_out, dim3(DM/128, 8192/128), dim3(256), 0, stream,
                       ytmp, x0t, wout, bout, out);
}

// Round 3
// 388.709 us; speedup vs baseline: 4.8435x; 2.8014x over previous
//
#include <hip/hip_runtime.h>
#include <math.h>

#define DM   1024
#define LL   4096
#define NB   2
#define E3   3072
#define FPI  3.14159265358979323846f

typedef __bf16 bf16x8 __attribute__((ext_vector_type(8)));
typedef float  f32x4  __attribute__((ext_vector_type(4)));

__device__ __forceinline__ unsigned short f2bf(float x) {
    unsigned u = __float_as_uint(x);
    u += 0x7fffu + ((u >> 16) & 1u);
    return (unsigned short)(u >> 16);
}
__device__ __forceinline__ float bf2f(unsigned short s) {
    return __uint_as_float(((unsigned)s) << 16);
}
__device__ __forceinline__ void gload16(void* lds, const void* g) {
    typedef const __attribute__((address_space(1))) unsigned int* gp_t;
    typedef __attribute__((address_space(3))) unsigned int* lp_t;
    __builtin_amdgcn_global_load_lds((gp_t)g, (lp_t)lds, 16, 0, 0);
}

// ---------------------------------------------------------------------------
// cvt: f32 -> bf16, vectorized x4
// ---------------------------------------------------------------------------
__global__ __launch_bounds__(256) void k_cvt_bf16(
    const float* __restrict__ in, ushort* __restrict__ out, int n4)
{
    int idx = blockIdx.x * 256 + threadIdx.x;
    int stride = gridDim.x * 256;
    for (int i = idx; i < n4; i += stride) {
        float4 v = reinterpret_cast<const float4*>(in)[i];
        ushort4 o;
        o.x = f2bf(v.x); o.y = f2bf(v.y); o.z = f2bf(v.z); o.w = f2bf(v.w);
        *reinterpret_cast<ushort4*>(out + 4 * i) = o;
    }
}

// ---------------------------------------------------------------------------
// MFMA bf16 GEMM: C[m][n] = sum_k A[m][k]*B[n][k] + bias[n]   (K=1024 fixed)
// 128x128 tile, BK=32, 256 thr (4 waves, 2x2), 16x16x32 MFMA, m97 structure.
// ---------------------------------------------------------------------------
__global__ __launch_bounds__(256) void k_gemm_bf16(
    const ushort* __restrict__ A, const ushort* __restrict__ B,
    const float* __restrict__ bias, float* __restrict__ C, int ldc)
{
    __shared__ ushort As[128 * 32];
    __shared__ ushort Bs[128 * 32];
    const int tid  = threadIdx.x;
    const int lane = tid & 63;
    const int w    = tid >> 6;
    const int wm   = (w >> 1) << 6, wn = (w & 1) << 6;
    const int m0   = blockIdx.y << 7, n0 = blockIdx.x << 7;

    f32x4 acc[4][4];
#pragma unroll
    for (int i = 0; i < 4; ++i)
#pragma unroll
        for (int j = 0; j < 4; ++j)
#pragma unroll
            for (int r = 0; r < 4; ++r) acc[i][j][r] = 0.f;

    // staging: pass p covers rows p*64 + (tid>>2), col-bytes (tid&3)*16
    const char* Ab = (const char*)A + ((size_t)(m0 + (tid >> 2)) << 11) + ((tid & 3) << 4);
    const char* Bb = (const char*)B + ((size_t)(n0 + (tid >> 2)) << 11) + ((tid & 3) << 4);
    char* AsD = (char*)As + tid * 16;
    char* BsD = (char*)Bs + tid * 16;
    const char* ap = (const char*)As + ((wm + (lane & 15)) << 6) + ((lane >> 4) << 4);
    const char* bp = (const char*)Bs + ((wn + (lane & 15)) << 6) + ((lane >> 4) << 4);

    for (int k0 = 0; k0 < 1024; k0 += 32) {
        __syncthreads();
        gload16(AsD,        Ab + k0 * 2);
        gload16(AsD + 4096, Ab + 131072 + k0 * 2);
        gload16(BsD,        Bb + k0 * 2);
        gload16(BsD + 4096, Bb + 131072 + k0 * 2);
        __syncthreads();
        bf16x8 af[4], bfr[4];
#pragma unroll
        for (int i = 0; i < 4; ++i) {
            af[i]  = *(const bf16x8*)(ap + (i << 10));
            bfr[i] = *(const bf16x8*)(bp + (i << 10));
        }
#pragma unroll
        for (int i = 0; i < 4; ++i)
#pragma unroll
            for (int j = 0; j < 4; ++j)
                acc[i][j] = __builtin_amdgcn_mfma_f32_16x16x32_bf16(
                    af[i], bfr[j], acc[i][j], 0, 0, 0);
    }
    const int er = (lane >> 4) << 2;
    const int ec = lane & 15;
#pragma unroll
    for (int i = 0; i < 4; ++i) {
        int row = m0 + wm + (i << 4) + er;
#pragma unroll
        for (int j = 0; j < 4; ++j) {
            int col = n0 + wn + (j << 4) + ec;
            float bz = bias[col];
            float* cp = C + (size_t)row * ldc + col;
#pragma unroll
            for (int r = 0; r < 4; ++r)
                cp[(size_t)r * ldc] = acc[i][j][r] + bz;
        }
    }
}

// ---------------------------------------------------------------------------
// K2: depthwise conv3 + split + gate + transpose to [b][c][t]  (f32 up)
// ---------------------------------------------------------------------------
__global__ __launch_bounds__(256) void k_dwconv(
    const float* __restrict__ up, const float* __restrict__ sfw,
    const float* __restrict__ sfb, float* __restrict__ x0t,
    float* __restrict__ vin)
{
    __shared__ float xT[32][65];
    __shared__ float vT[32][65];
    const int b  = blockIdx.z;
    const int t0 = blockIdx.y * 64;
    const int c0 = blockIdx.x * 32;
    const int tid = threadIdx.x;
    const int cL = tid & 31, tL = tid >> 5;
    const float* upb = up + (size_t)b * LL * E3;
    const int c = c0 + cL;

#pragma unroll
    for (int r = 0; r < 8; ++r) {
        int t_local = (r << 3) + tL;
        int t = t0 + t_local;
        float res[3];
#pragma unroll
        for (int s3 = 0; s3 < 3; ++s3) {
            int e = c + (s3 << 10);
            float w0 = sfw[e*3+0], w1 = sfw[e*3+1], w2 = sfw[e*3+2];
            float xa = (t >= 2) ? upb[(size_t)(t-2)*E3 + e] : 0.f;
            float xb = (t >= 1) ? upb[(size_t)(t-1)*E3 + e] : 0.f;
            float xc = upb[(size_t)t*E3 + e];
            res[s3] = w0*xa + w1*xb + w2*xc + sfb[e];
        }
        xT[cL][t_local] = res[0];
        vT[cL][t_local] = res[1] * res[2];
    }
    __syncthreads();
    const int cW = tid >> 3, q = tid & 7;
    float tmp[8];
#pragma unroll
    for (int i = 0; i < 8; ++i) tmp[i] = xT[cW][8*q + i];
    size_t off = ((size_t)b * DM + c0 + cW) * LL + t0 + 8*q;
    *reinterpret_cast<float4*>(x0t + off)     = make_float4(tmp[0], tmp[1], tmp[2], tmp[3]);
    *reinterpret_cast<float4*>(x0t + off + 4) = make_float4(tmp[4], tmp[5], tmp[6], tmp[7]);
#pragma unroll
    for (int i = 0; i < 8; ++i) tmp[i] = vT[cW][8*q + i];
    *reinterpret_cast<float4*>(vin + off)     = make_float4(tmp[0], tmp[1], tmp[2], tmp[3]);
    *reinterpret_cast<float4*>(vin + off + 4) = make_float4(tmp[4], tmp[5], tmp[6], tmp[7]);
}

// ---------------------------------------------------------------------------
// K3a: filter MLP
// ---------------------------------------------------------------------------
__global__ __launch_bounds__(256) void k_filt_mlp(
    const float* __restrict__ z, const float* __restrict__ w0,
    const float* __restrict__ b0, const float* __restrict__ fr,
    const float* __restrict__ w1, const float* __restrict__ b1,
    const float* __restrict__ w2, const float* __restrict__ b2,
    float* __restrict__ H3)
{
    __shared__ float w1t[64 * 65];
    __shared__ float w2t[64 * 65];
    __shared__ float hb[4][64];
    const int tid = threadIdx.x;
    for (int idx = tid; idx < 4096; idx += 256) {
        int j = idx >> 6, m = idx & 63;
        w1t[m*65 + j] = w1[idx];
        w2t[m*65 + j] = w2[idx];
    }
    __syncthreads();
    const int tl = tid >> 6, j = tid & 63;
    const float frj = fr[j];
    const float b0j = b0[j], b1j = b1[j], b2j = b2[j];
    const float w00 = w0[j*3+0], w01 = w0[j*3+1], w02 = w0[j*3+2];
    const int t0 = blockIdx.x * 64;
    for (int r = 0; r < 16; ++r) {
        int t = t0 + r*4 + tl;
        float z0 = z[t*3+0], z1 = z[t*3+1], z2 = z[t*3+2];
        float h = sinf(frj * (b0j + z0*w00 + z1*w01 + z2*w02));
        hb[tl][j] = h;
        __syncthreads();
        float s = b1j;
#pragma unroll
        for (int m = 0; m < 64; ++m) s = fmaf(hb[tl][m], w1t[m*65 + j], s);
        __syncthreads();
        h = sinf(frj * s);
        hb[tl][j] = h;
        __syncthreads();
        s = b2j;
#pragma unroll
        for (int m = 0; m < 64; ++m) s = fmaf(hb[tl][m], w2t[m*65 + j], s);
        h = sinf(frj * s);
        H3[(size_t)t * 64 + j] = h;
        __syncthreads();
    }
}

// ---------------------------------------------------------------------------
// K3b: kf[d][t] = (H3 @ wf^T) * exp-decay
// ---------------------------------------------------------------------------
__global__ __launch_bounds__(256) void k_filt_k(
    const float* __restrict__ H3, const float* __restrict__ wf,
    float* __restrict__ kf)
{
    __shared__ float Hs[64][65];
    __shared__ float Ws[64][65];
    const int tid = threadIdx.x;
    const int t0 = blockIdx.x * 64, d0 = blockIdx.y * 64;
    for (int idx = tid; idx < 4096; idx += 256) {
        int r = idx >> 6, cc = idx & 63;
        Hs[r][cc] = H3[(size_t)(t0 + r) * 64 + cc];
        Ws[r][cc] = wf[(size_t)(d0 + r) * 64 + cc];
    }
    __syncthreads();
    const int tx = tid & 15, ty = tid >> 4;
    float acc[4][4];
#pragma unroll
    for (int i = 0; i < 4; ++i)
#pragma unroll
        for (int jj = 0; jj < 4; ++jj) acc[i][jj] = 0.f;
#pragma unroll
    for (int j = 0; j < 64; ++j) {
        float wv[4], hv[4];
#pragma unroll
        for (int i = 0; i < 4; ++i) wv[i] = Ws[4*ty + i][j];
#pragma unroll
        for (int i = 0; i < 4; ++i) hv[i] = Hs[4*tx + i][j];
#pragma unroll
        for (int i = 0; i < 4; ++i)
#pragma unroll
            for (int jj = 0; jj < 4; ++jj) acc[i][jj] = fmaf(wv[i], hv[jj], acc[i][jj]);
    }
    const float mind = -3.0701134573253944f;
    const float maxd = -15.350567286626972f;
#pragma unroll
    for (int i = 0; i < 4; ++i) {
        int d = d0 + 4*ty + i;
        float delta = fabsf(mind + (maxd - mind) * ((float)d / 1023.f));
#pragma unroll
        for (int jj = 0; jj < 4; ++jj) {
            int t = t0 + 4*tx + jj;
            float tn = (float)t / 4095.f;
            kf[(size_t)d * LL + t] = acc[i][jj] * expf(-tn * delta);
        }
    }
}

// ---------------------------------------------------------------------------
// FFT helpers (8192-pt, DIF fwd natural->scrambled, DIT inv back)
// ---------------------------------------------------------------------------
__device__ __forceinline__ int pidx(int p) { return p + (p >> 4); }

__device__ __forceinline__ float2 cmul(float2 a, float2 b) {
    return make_float2(a.x*b.x - a.y*b.y, a.x*b.y + a.y*b.x);
}

__device__ void fft_lds_fwd(float2* buf, int tid) {
    for (int h = 4096; h >= 16; h >>= 1) {
        float rinv = -FPI / (float)h;
        __syncthreads();
#pragma unroll
        for (int r = 0; r < 8; ++r) {
            int bf = (r << 9) + tid;
            int pos = bf & (h - 1);
            int i = 2 * bf - pos;
            float2 a = buf[pidx(i)];
            float2 b = buf[pidx(i + h)];
            float2 s = make_float2(a.x + b.x, a.y + b.y);
            float2 d = make_float2(a.x - b.x, a.y - b.y);
            float sn, cs;
            __sincosf(rinv * (float)pos, &sn, &cs);
            buf[pidx(i)]     = s;
            buf[pidx(i + h)] = make_float2(d.x*cs - d.y*sn, d.x*sn + d.y*cs);
        }
    }
    __syncthreads();
}

__device__ void fft_lds_inv(float2* buf, int tid) {
    for (int h = 16; h <= 4096; h <<= 1) {
        float rinv = FPI / (float)h;
        __syncthreads();
#pragma unroll
        for (int r = 0; r < 8; ++r) {
            int bf = (r << 9) + tid;
            int pos = bf & (h - 1);
            int i = 2 * bf - pos;
            float2 a = buf[pidx(i)];
            float2 b = buf[pidx(i + h)];
            float sn, cs;
            __sincosf(rinv * (float)pos, &sn, &cs);
            float2 bt = make_float2(b.x*cs - b.y*sn, b.x*sn + b.y*cs);
            buf[pidx(i)]     = make_float2(a.x + bt.x, a.y + bt.y);
            buf[pidx(i + h)] = make_float2(a.x - bt.x, a.y - bt.y);
        }
    }
    __syncthreads();
}

__device__ __forceinline__ void fft_reg_fwd(float2* c) {
    const float W16r[8] = {1.f, 0.92387953f, 0.70710678f, 0.38268343f,
                           0.f, -0.38268343f, -0.70710678f, -0.92387953f};
    const float W16i[8] = {0.f, -0.38268343f, -0.70710678f, -0.92387953f,
                           -1.f, -0.92387953f, -0.70710678f, -0.38268343f};
#pragma unroll
    for (int k = 0; k < 8; ++k) {
        float2 a = c[k], b = c[k+8];
        float2 d = make_float2(a.x - b.x, a.y - b.y);
        c[k]   = make_float2(a.x + b.x, a.y + b.y);
        c[k+8] = cmul(d, make_float2(W16r[k], W16i[k]));
    }
    const float W8r[4] = {1.f, 0.70710678f, 0.f, -0.70710678f};
    const float W8i[4] = {0.f, -0.70710678f, -1.f, -0.70710678f};
#pragma unroll
    for (int blk = 0; blk < 16; blk += 8)
#pragma unroll
        for (int k = 0; k < 4; ++k) {
            float2 a = c[blk+k], b = c[blk+k+4];
            float2 d = make_float2(a.x - b.x, a.y - b.y);
            c[blk+k]   = make_float2(a.x + b.x, a.y + b.y);
            c[blk+k+4] = cmul(d, make_float2(W8r[k], W8i[k]));
        }
#pragma unroll
    for (int blk = 0; blk < 16; blk += 4) {
        {   float2 a = c[blk], b = c[blk+2];
            c[blk]   = make_float2(a.x + b.x, a.y + b.y);
            c[blk+2] = make_float2(a.x - b.x, a.y - b.y); }
        {   float2 a = c[blk+1], b = c[blk+3];
            float2 d = make_float2(a.x - b.x, a.y - b.y);
            c[blk+1] = make_float2(a.x + b.x, a.y + b.y);
            c[blk+3] = make_float2(d.y, -d.x); }
    }
#pragma unroll
    for (int blk = 0; blk < 16; blk += 2) {
        float2 a = c[blk], b = c[blk+1];
        c[blk]   = make_float2(a.x + b.x, a.y + b.y);
        c[blk+1] = make_float2(a.x - b.x, a.y - b.y);
    }
}

__device__ __forceinline__ void fft_reg_inv(float2* c) {
#pragma unroll
    for (int blk = 0; blk < 16; blk += 2) {
        float2 a = c[blk], b = c[blk+1];
        c[blk]   = make_float2(a.x + b.x, a.y + b.y);
        c[blk+1] = make_float2(a.x - b.x, a.y - b.y);
    }
#pragma unroll
    for (int blk = 0; blk < 16; blk += 4) {
        {   float2 a = c[blk], b = c[blk+2];
            c[blk]   = make_float2(a.x + b.x, a.y + b.y);
            c[blk+2] = make_float2(a.x - b.x, a.y - b.y); }
        {   float2 a = c[blk+1], b = c[blk+3];
            float2 bt = make_float2(-b.y, b.x);
            bt = make_float2(-c[blk+3].y, c[blk+3].x);
            c[blk+1] = make_float2(a.x + bt.x, a.y + bt.y);
            c[blk+3] = make_float2(a.x - bt.x, a.y - bt.y); }
    }
    const float W8r[4] = {1.f, 0.70710678f, 0.f, -0.70710678f};
    const float W8i[4] = {0.f, 0.70710678f, 1.f, 0.70710678f};
#pragma unroll
    for (int blk = 0; blk < 16; blk += 8)
#pragma unroll
        for (int k = 0; k < 4; ++k) {
            float2 a = c[blk+k], b = c[blk+k+4];
            float2 bt = cmul(b, make_float2(W8r[k], W8i[k]));
            c[blk+k]   = make_float2(a.x + bt.x, a.y + bt.y);
            c[blk+k+4] = make_float2(a.x - bt.x, a.y - bt.y);
        }
    const float W16r[8] = {1.f, 0.92387953f, 0.70710678f, 0.38268343f,
                           0.f, -0.38268343f, -0.70710678f, -0.92387953f};
    const float W16i[8] = {0.f, 0.38268343f, 0.70710678f, 0.92387953f,
                           1.f, 0.92387953f, 0.70710678f, 0.38268343f};
#pragma unroll
    for (int k = 0; k < 8; ++k) {
        float2 a = c[k], b = c[k+8];
        float2 bt = cmul(b, make_float2(W16r[k], W16i[k]));
        c[k]   = make_float2(a.x + bt.x, a.y + bt.y);
        c[k+8] = make_float2(a.x - bt.x, a.y - bt.y);
    }
}

// ---------------------------------------------------------------------------
// K4a: kernel spectrum (scrambled, pre-scaled by 1/8192)
// ---------------------------------------------------------------------------
__global__ __launch_bounds__(512) void k_kfft(
    const float* __restrict__ kf, float2* __restrict__ Kf)
{
    __shared__ float2 buf[8704];
    const int d = blockIdx.x, tid = threadIdx.x;
    const float* krow = kf + (size_t)d * LL;
    for (int i = tid; i < 1024; i += 512) {
        float4 k4 = reinterpret_cast<const float4*>(krow)[i];
        int p = 4 * i;
        buf[pidx(p+0)] = make_float2(k4.x, 0.f);
        buf[pidx(p+1)] = make_float2(k4.y, 0.f);
        buf[pidx(p+2)] = make_float2(k4.z, 0.f);
        buf[pidx(p+3)] = make_float2(k4.w, 0.f);
    }
    for (int p = 4096 + tid; p < 8192; p += 512)
        buf[pidx(p)] = make_float2(0.f, 0.f);
    fft_lds_fwd(buf, tid);
    float2 c[16];
    const int p0 = tid * 16;
#pragma unroll
    for (int j = 0; j < 16; ++j) c[j] = buf[pidx(p0 + j)];
    fft_reg_fwd(c);
    float2* outp = Kf + (size_t)d * 8192 + p0;
#pragma unroll
    for (int j = 0; j < 16; ++j)
        outp[j] = make_float2(c[j].x * (1.f/8192.f), c[j].y * (1.f/8192.f));
}

// ---------------------------------------------------------------------------
// K4b: fft conv + D*v skip + x0 gate, bf16 output yg[b][d][t]
// ---------------------------------------------------------------------------
__global__ __launch_bounds__(512) void k_fftconv(
    const float* __restrict__ vin, const float2* __restrict__ Kf,
    const float* __restrict__ x0t, const float* __restrict__ Dp,
    ushort* __restrict__ yg)
{
    __shared__ float2 buf[8704];
    const int d = blockIdx.x, b = blockIdx.y, tid = threadIdx.x;
    const float* vrow = vin + ((size_t)b * DM + d) * LL;
    for (int i = tid; i < 1024; i += 512) {
        float4 v4 = reinterpret_cast<const float4*>(vrow)[i];
        int p = 4 * i;
        buf[pidx(p+0)] = make_float2(v4.x, 0.f);
        buf[pidx(p+1)] = make_float2(v4.y, 0.f);
        buf[pidx(p+2)] = make_float2(v4.z, 0.f);
        buf[pidx(p+3)] = make_float2(v4.w, 0.f);
    }
    for (int p = 4096 + tid; p < 8192; p += 512)
        buf[pidx(p)] = make_float2(0.f, 0.f);
    fft_lds_fwd(buf, tid);
    float2 c[16];
    const int p0 = tid * 16;
#pragma unroll
    for (int j = 0; j < 16; ++j) c[j] = buf[pidx(p0 + j)];
    fft_reg_fwd(c);
    const float2* kfr = Kf + (size_t)d * 8192 + p0;
#pragma unroll
    for (int j = 0; j < 16; ++j) c[j] = cmul(c[j], kfr[j]);
    fft_reg_inv(c);
#pragma unroll
    for (int j = 0; j < 16; ++j) buf[pidx(p0 + j)] = c[j];
    fft_lds_inv(buf, tid);
    const float Dd = Dp[d];
    const float* xrow = x0t + ((size_t)b * DM + d) * LL;
    ushort* orow = yg + ((size_t)b * DM + d) * LL;
    for (int i = tid; i < 1024; i += 512) {
        float4 v4 = reinterpret_cast<const float4*>(vrow)[i];
        float4 x4 = reinterpret_cast<const float4*>(xrow)[i];
        int p = 4 * i;
        ushort4 st;
        st.x = f2bf((buf[pidx(p+0)].x + Dd * v4.x) * x4.x);
        st.y = f2bf((buf[pidx(p+1)].x + Dd * v4.y) * x4.y);
        st.z = f2bf((buf[pidx(p+2)].x + Dd * v4.z) * x4.z);
        st.w = f2bf((buf[pidx(p+3)].x + Dd * v4.w) * x4.w);
        *reinterpret_cast<ushort4*>(orow + p) = st;
    }
}

// ---------------------------------------------------------------------------
// K_tr: yg[b][d][t] (bf16) -> Ag[b][t][d] (bf16), 64x64 LDS tiles
// ---------------------------------------------------------------------------
__global__ __launch_bounds__(256) void k_tr(
    const ushort* __restrict__ yg, ushort* __restrict__ Ag)
{
    __shared__ ushort S[64][72];
    const int b  = blockIdx.z;
    const int d0 = blockIdx.y * 64;
    const int t0 = blockIdx.x * 64;
    const int tid = threadIdx.x;
#pragma unroll
    for (int p = 0; p < 2; ++p) {
        int idx = p * 256 + tid;
        int dr = idx >> 3, c8 = (idx & 7) << 3;
        uint4 v = *reinterpret_cast<const uint4*>(
            yg + ((size_t)b * DM + d0 + dr) * LL + t0 + c8);
        *reinterpret_cast<uint4*>(&S[dr][c8]) = v;
    }
    __syncthreads();
#pragma unroll
    for (int p = 0; p < 2; ++p) {
        int idx = p * 256 + tid;
        int tr = idx >> 3, dq = (idx & 7) << 3;
        ushort tmp[8] __attribute__((aligned(16)));
#pragma unroll
        for (int q = 0; q < 8; ++q) tmp[q] = S[dq + q][tr];
        *reinterpret_cast<uint4*>(Ag + ((size_t)b * LL + t0 + tr) * DM + d0 + dq) =
            *reinterpret_cast<uint4*>(tmp);
    }
}

// ---------------------------------------------------------------------------
extern "C" void kernel_launch(void* const* d_in, const int* in_sizes, int n_in,
                              void* d_out, int out_size, void* d_ws, size_t ws_size,
                              hipStream_t stream)
{
    if (n_in < 17) return;
    const float* u    = (const float*)d_in[0];
    const float* w_in = (const float*)d_in[1];
    const float* b_in = (const float*)d_in[2];
    const float* sf_w = (const float*)d_in[3];
    const float* sf_b = (const float*)d_in[4];
    const float* z    = (const float*)d_in[5];
    const float* w0   = (const float*)d_in[6];
    const float* b0   = (const float*)d_in[7];
    const float* freq = (const float*)d_in[8];
    const float* w1   = (const float*)d_in[9];
    const float* b1   = (const float*)d_in[10];
    const float* w2   = (const float*)d_in[11];
    const float* b2   = (const float*)d_in[12];
    const float* wf   = (const float*)d_in[13];
    const float* Dp   = (const float*)d_in[14];
    const float* wout = (const float*)d_in[15];
    const float* bout = (const float*)d_in[16];
    float* out = (float*)d_out;
    float* ws  = (float*)d_ws;

    // Overlaid workspace (float offsets). Timeline P1..P7:
    //  R0 [0, 25165824): up f32 (P2-P3); then Kf [0,16.78M) (P4-P5),
    //      kf [16.78M,20.97M) (P4) -> yg bf16 same slot (P5-P6),
    //      H3 [20.97M,+0.26M) (P4) -> Ag bf16 [20.97M,25.17M) (P6-P7)
    //  R1 [25165824, +8388608): u_bf16 (P1-P2) -> x0t f32 (P3-P5)
    //  R2 [33554432, +8388608): w_in_bf16 (P1-P2) -> vin f32 (P3-P5)
    //      -> wout_bf16 (P6-P7)
    float*  up    = ws;
    float2* Kf    = (float2*)ws;
    float*  kfbuf = ws + 16777216;
    ushort* yg    = (ushort*)(ws + 16777216);
    float*  H3    = ws + 20971520;
    ushort* Ag    = (ushort*)(ws + 20971520);
    ushort* ub    = (ushort*)(ws + 25165824);
    float*  x0t   = ws + 25165824;
    ushort* wb    = (ushort*)(ws + 33554432);
    float*  vin   = ws + 33554432;
    ushort* woutb = (ushort*)(ws + 33554432);
    const size_t NEED = (size_t)41943040 * 4;
    if (ws_size < NEED) return;

    // P1: bf16 conversions of u and w_in
    hipLaunchKernelGGL(k_cvt_bf16, dim3(2048), dim3(256), 0, stream, u, ub, 2097152);
    hipLaunchKernelGGL(k_cvt_bf16, dim3(2048), dim3(256), 0, stream, w_in, wb, 786432);
    // P2: up = u @ w_in^T + b_in   (MFMA)
    hipLaunchKernelGGL(k_gemm_bf16, dim3(E3/128, 8192/128), dim3(256), 0, stream,
                       ub, wb, b_in, up, E3);
    // P3: dwconv + split + gate + transpose
    hipLaunchKernelGGL(k_dwconv,   dim3(DM/32, LL/64, NB), dim3(256), 0, stream,
                       up, sf_w, sf_b, x0t, vin);
    // P4: filter construction
    hipLaunchKernelGGL(k_filt_mlp, dim3(LL/64), dim3(256), 0, stream,
                       z, w0, b0, freq, w1, b1, w2, b2, H3);
    hipLaunchKernelGGL(k_filt_k,   dim3(LL/64, DM/64), dim3(256), 0, stream,
                       H3, wf, kfbuf);
    hipLaunchKernelGGL(k_kfft,     dim3(DM), dim3(512), 0, stream,
                       kfbuf, Kf);
    // P5: fft conv + skip + gate -> yg bf16
    hipLaunchKernelGGL(k_fftconv,  dim3(DM, NB), dim3(512), 0, stream,
                       vin, Kf, x0t, Dp, yg);
    // P6: wout -> bf16 ; transpose yg -> Ag
    hipLaunchKernelGGL(k_cvt_bf16, dim3(1024), dim3(256), 0, stream, wout, woutb, 262144);
    hipLaunchKernelGGL(k_tr,       dim3(LL/64, DM/64, NB), dim3(256), 0, stream,
                       yg, Ag);
    // P7: out = Ag @ wout^T + b_out  (MFMA)
    hipLaunchKernelGGL(k_gemm_bf16, dim3(DM/128, 8192/128), dim3(256), 0, stream,
                       Ag, woutb, bout, out, DM);
}

// Round 4
// 321.570 us; speedup vs baseline: 5.8547x; 1.2088x over previous
//
#include <hip/hip_runtime.h>
#include <math.h>

#define DM   1024
#define LL   4096
#define NB   2
#define E3   3072
#define FPI  3.14159265358979323846f

typedef __bf16 bf16x8 __attribute__((ext_vector_type(8)));
typedef float  f32x4  __attribute__((ext_vector_type(4)));

__device__ __forceinline__ unsigned short f2bf(float x) {
    unsigned u = __float_as_uint(x);
    u += 0x7fffu + ((u >> 16) & 1u);
    return (unsigned short)(u >> 16);
}
__device__ __forceinline__ void gload16(void* lds, const void* g) {
    typedef const __attribute__((address_space(1))) unsigned int* gp_t;
    typedef __attribute__((address_space(3))) unsigned int* lp_t;
    __builtin_amdgcn_global_load_lds((gp_t)g, (lp_t)lds, 16, 0, 0);
}

// ---------------------------------------------------------------------------
// cvt: f32 -> bf16, vectorized x4
// ---------------------------------------------------------------------------
__global__ __launch_bounds__(256) void k_cvt_bf16(
    const float* __restrict__ in, ushort* __restrict__ out, int n4)
{
    int idx = blockIdx.x * 256 + threadIdx.x;
    int stride = gridDim.x * 256;
    for (int i = idx; i < n4; i += stride) {
        float4 v = reinterpret_cast<const float4*>(in)[i];
        ushort4 o;
        o.x = f2bf(v.x); o.y = f2bf(v.y); o.z = f2bf(v.z); o.w = f2bf(v.w);
        *reinterpret_cast<ushort4*>(out + 4 * i) = o;
    }
}

// ---------------------------------------------------------------------------
// MFMA bf16 GEMM: C[m][n] = sum_k A[m][k]*B[n][k] + bias[n]   (K=1024 fixed)
// ---------------------------------------------------------------------------
__global__ __launch_bounds__(256) void k_gemm_bf16(
    const ushort* __restrict__ A, const ushort* __restrict__ B,
    const float* __restrict__ bias, float* __restrict__ C, int ldc)
{
    __shared__ ushort As[128 * 32];
    __shared__ ushort Bs[128 * 32];
    const int tid  = threadIdx.x;
    const int lane = tid & 63;
    const int w    = tid >> 6;
    const int wm   = (w >> 1) << 6, wn = (w & 1) << 6;
    const int m0   = blockIdx.y << 7, n0 = blockIdx.x << 7;

    f32x4 acc[4][4];
#pragma unroll
    for (int i = 0; i < 4; ++i)
#pragma unroll
        for (int j = 0; j < 4; ++j)
#pragma unroll
            for (int r = 0; r < 4; ++r) acc[i][j][r] = 0.f;

    const char* Ab = (const char*)A + ((size_t)(m0 + (tid >> 2)) << 11) + ((tid & 3) << 4);
    const char* Bb = (const char*)B + ((size_t)(n0 + (tid >> 2)) << 11) + ((tid & 3) << 4);
    char* AsD = (char*)As + tid * 16;
    char* BsD = (char*)Bs + tid * 16;
    const char* ap = (const char*)As + ((wm + (lane & 15)) << 6) + ((lane >> 4) << 4);
    const char* bp = (const char*)Bs + ((wn + (lane & 15)) << 6) + ((lane >> 4) << 4);

    for (int k0 = 0; k0 < 1024; k0 += 32) {
        __syncthreads();
        gload16(AsD,        Ab + k0 * 2);
        gload16(AsD + 4096, Ab + 131072 + k0 * 2);
        gload16(BsD,        Bb + k0 * 2);
        gload16(BsD + 4096, Bb + 131072 + k0 * 2);
        __syncthreads();
        bf16x8 af[4], bfr[4];
#pragma unroll
        for (int i = 0; i < 4; ++i) {
            af[i]  = *(const bf16x8*)(ap + (i << 10));
            bfr[i] = *(const bf16x8*)(bp + (i << 10));
        }
#pragma unroll
        for (int i = 0; i < 4; ++i)
#pragma unroll
            for (int j = 0; j < 4; ++j)
                acc[i][j] = __builtin_amdgcn_mfma_f32_16x16x32_bf16(
                    af[i], bfr[j], acc[i][j], 0, 0, 0);
    }
    const int er = (lane >> 4) << 2;
    const int ec = lane & 15;
#pragma unroll
    for (int i = 0; i < 4; ++i) {
        int row = m0 + wm + (i << 4) + er;
#pragma unroll
        for (int j = 0; j < 4; ++j) {
            int col = n0 + wn + (j << 4) + ec;
            float bz = bias[col];
            float* cp = C + (size_t)row * ldc + col;
#pragma unroll
            for (int r = 0; r < 4; ++r)
                cp[(size_t)r * ldc] = acc[i][j][r] + bz;
        }
    }
}

// ---------------------------------------------------------------------------
// K2: depthwise conv3 + split + gate + transpose to [b][c][t]
// ---------------------------------------------------------------------------
__global__ __launch_bounds__(256) void k_dwconv(
    const float* __restrict__ up, const float* __restrict__ sfw,
    const float* __restrict__ sfb, float* __restrict__ x0t,
    float* __restrict__ vin)
{
    __shared__ float xT[32][65];
    __shared__ float vT[32][65];
    const int b  = blockIdx.z;
    const int t0 = blockIdx.y * 64;
    const int c0 = blockIdx.x * 32;
    const int tid = threadIdx.x;
    const int cL = tid & 31, tL = tid >> 5;
    const float* upb = up + (size_t)b * LL * E3;
    const int c = c0 + cL;

#pragma unroll
    for (int r = 0; r < 8; ++r) {
        int t_local = (r << 3) + tL;
        int t = t0 + t_local;
        float res[3];
#pragma unroll
        for (int s3 = 0; s3 < 3; ++s3) {
            int e = c + (s3 << 10);
            float w0 = sfw[e*3+0], w1 = sfw[e*3+1], w2 = sfw[e*3+2];
            float xa = (t >= 2) ? upb[(size_t)(t-2)*E3 + e] : 0.f;
            float xb = (t >= 1) ? upb[(size_t)(t-1)*E3 + e] : 0.f;
            float xc = upb[(size_t)t*E3 + e];
            res[s3] = w0*xa + w1*xb + w2*xc + sfb[e];
        }
        xT[cL][t_local] = res[0];
        vT[cL][t_local] = res[1] * res[2];
    }
    __syncthreads();
    const int cW = tid >> 3, q = tid & 7;
    float tmp[8];
#pragma unroll
    for (int i = 0; i < 8; ++i) tmp[i] = xT[cW][8*q + i];
    size_t off = ((size_t)b * DM + c0 + cW) * LL + t0 + 8*q;
    *reinterpret_cast<float4*>(x0t + off)     = make_float4(tmp[0], tmp[1], tmp[2], tmp[3]);
    *reinterpret_cast<float4*>(x0t + off + 4) = make_float4(tmp[4], tmp[5], tmp[6], tmp[7]);
#pragma unroll
    for (int i = 0; i < 8; ++i) tmp[i] = vT[cW][8*q + i];
    *reinterpret_cast<float4*>(vin + off)     = make_float4(tmp[0], tmp[1], tmp[2], tmp[3]);
    *reinterpret_cast<float4*>(vin + off + 4) = make_float4(tmp[4], tmp[5], tmp[6], tmp[7]);
}

// ---------------------------------------------------------------------------
// K3a: filter MLP
// ---------------------------------------------------------------------------
__global__ __launch_bounds__(256) void k_filt_mlp(
    const float* __restrict__ z, const float* __restrict__ w0,
    const float* __restrict__ b0, const float* __restrict__ fr,
    const float* __restrict__ w1, const float* __restrict__ b1,
    const float* __restrict__ w2, const float* __restrict__ b2,
    float* __restrict__ H3)
{
    __shared__ float w1t[64 * 65];
    __shared__ float w2t[64 * 65];
    __shared__ float hb[4][64];
    const int tid = threadIdx.x;
    for (int idx = tid; idx < 4096; idx += 256) {
        int j = idx >> 6, m = idx & 63;
        w1t[m*65 + j] = w1[idx];
        w2t[m*65 + j] = w2[idx];
    }
    __syncthreads();
    const int tl = tid >> 6, j = tid & 63;
    const float frj = fr[j];
    const float b0j = b0[j], b1j = b1[j], b2j = b2[j];
    const float w00 = w0[j*3+0], w01 = w0[j*3+1], w02 = w0[j*3+2];
    const int t0 = blockIdx.x * 64;
    for (int r = 0; r < 16; ++r) {
        int t = t0 + r*4 + tl;
        float z0 = z[t*3+0], z1 = z[t*3+1], z2 = z[t*3+2];
        float h = sinf(frj * (b0j + z0*w00 + z1*w01 + z2*w02));
        hb[tl][j] = h;
        __syncthreads();
        float s = b1j;
#pragma unroll
        for (int m = 0; m < 64; ++m) s = fmaf(hb[tl][m], w1t[m*65 + j], s);
        __syncthreads();
        h = sinf(frj * s);
        hb[tl][j] = h;
        __syncthreads();
        s = b2j;
#pragma unroll
        for (int m = 0; m < 64; ++m) s = fmaf(hb[tl][m], w2t[m*65 + j], s);
        h = sinf(frj * s);
        H3[(size_t)t * 64 + j] = h;
        __syncthreads();
    }
}

// ---------------------------------------------------------------------------
// K3b: kf[d][t] = (H3 @ wf^T) * exp-decay
// ---------------------------------------------------------------------------
__global__ __launch_bounds__(256) void k_filt_k(
    const float* __restrict__ H3, const float* __restrict__ wf,
    float* __restrict__ kf)
{
    __shared__ float Hs[64][65];
    __shared__ float Ws[64][65];
    const int tid = threadIdx.x;
    const int t0 = blockIdx.x * 64, d0 = blockIdx.y * 64;
    for (int idx = tid; idx < 4096; idx += 256) {
        int r = idx >> 6, cc = idx & 63;
        Hs[r][cc] = H3[(size_t)(t0 + r) * 64 + cc];
        Ws[r][cc] = wf[(size_t)(d0 + r) * 64 + cc];
    }
    __syncthreads();
    const int tx = tid & 15, ty = tid >> 4;
    float acc[4][4];
#pragma unroll
    for (int i = 0; i < 4; ++i)
#pragma unroll
        for (int jj = 0; jj < 4; ++jj) acc[i][jj] = 0.f;
#pragma unroll
    for (int j = 0; j < 64; ++j) {
        float wv[4], hv[4];
#pragma unroll
        for (int i = 0; i < 4; ++i) wv[i] = Ws[4*ty + i][j];
#pragma unroll
        for (int i = 0; i < 4; ++i) hv[i] = Hs[4*tx + i][j];
#pragma unroll
        for (int i = 0; i < 4; ++i)
#pragma unroll
            for (int jj = 0; jj < 4; ++jj) acc[i][jj] = fmaf(wv[i], hv[jj], acc[i][jj]);
    }
    const float mind = -3.0701134573253944f;
    const float maxd = -15.350567286626972f;
#pragma unroll
    for (int i = 0; i < 4; ++i) {
        int d = d0 + 4*ty + i;
        float delta = fabsf(mind + (maxd - mind) * ((float)d / 1023.f));
#pragma unroll
        for (int jj = 0; jj < 4; ++jj) {
            int t = t0 + 4*tx + jj;
            float tn = (float)t / 4095.f;
            kf[(size_t)d * LL + t] = acc[i][jj] * expf(-tn * delta);
        }
    }
}

// ---------------------------------------------------------------------------
// FFT helpers (8192-pt, DIF fwd natural->scrambled, DIT inv back).
// Stage h=4096 of the forward is fused into the load (top half is zero).
// ---------------------------------------------------------------------------
__device__ __forceinline__ int pidx(int p) { return p + (p >> 4); }

__device__ __forceinline__ float2 cmul(float2 a, float2 b) {
    return make_float2(a.x*b.x - a.y*b.y, a.x*b.y + a.y*b.x);
}

__device__ void fft_lds_fwd(float2* buf, int tid) {
    for (int h = 2048; h >= 16; h >>= 1) {     // h=4096 fused into load
        float rinv = -FPI / (float)h;
        __syncthreads();
#pragma unroll
        for (int r = 0; r < 8; ++r) {
            int bf = (r << 9) + tid;
            int pos = bf & (h - 1);
            int i = 2 * bf - pos;
            float2 a = buf[pidx(i)];
            float2 b = buf[pidx(i + h)];
            float2 s = make_float2(a.x + b.x, a.y + b.y);
            float2 d = make_float2(a.x - b.x, a.y - b.y);
            float sn, cs;
            __sincosf(rinv * (float)pos, &sn, &cs);
            buf[pidx(i)]     = s;
            buf[pidx(i + h)] = make_float2(d.x*cs - d.y*sn, d.x*sn + d.y*cs);
        }
    }
    __syncthreads();
}

__device__ void fft_lds_inv(float2* buf, int tid) {
    for (int h = 16; h <= 4096; h <<= 1) {
        float rinv = FPI / (float)h;
        __syncthreads();
#pragma unroll
        for (int r = 0; r < 8; ++r) {
            int bf = (r << 9) + tid;
            int pos = bf & (h - 1);
            int i = 2 * bf - pos;
            float2 a = buf[pidx(i)];
            float2 b = buf[pidx(i + h)];
            float sn, cs;
            __sincosf(rinv * (float)pos, &sn, &cs);
            float2 bt = make_float2(b.x*cs - b.y*sn, b.x*sn + b.y*cs);
            buf[pidx(i)]     = make_float2(a.x + bt.x, a.y + bt.y);
            buf[pidx(i + h)] = make_float2(a.x - bt.x, a.y - bt.y);
        }
    }
    __syncthreads();
}

__device__ __forceinline__ void fft_reg_fwd(float2* c) {
    const float W16r[8] = {1.f, 0.92387953f, 0.70710678f, 0.38268343f,
                           0.f, -0.38268343f, -0.70710678f, -0.92387953f};
    const float W16i[8] = {0.f, -0.38268343f, -0.70710678f, -0.92387953f,
                           -1.f, -0.92387953f, -0.70710678f, -0.38268343f};
#pragma unroll
    for (int k = 0; k < 8; ++k) {
        float2 a = c[k], b = c[k+8];
        float2 d = make_float2(a.x - b.x, a.y - b.y);
        c[k]   = make_float2(a.x + b.x, a.y + b.y);
        c[k+8] = cmul(d, make_float2(W16r[k], W16i[k]));
    }
    const float W8r[4] = {1.f, 0.70710678f, 0.f, -0.70710678f};
    const float W8i[4] = {0.f, -0.70710678f, -1.f, -0.70710678f};
#pragma unroll
    for (int blk = 0; blk < 16; blk += 8)
#pragma unroll
        for (int k = 0; k < 4; ++k) {
            float2 a = c[blk+k], b = c[blk+k+4];
            float2 d = make_float2(a.x - b.x, a.y - b.y);
            c[blk+k]   = make_float2(a.x + b.x, a.y + b.y);
            c[blk+k+4] = cmul(d, make_float2(W8r[k], W8i[k]));
        }
#pragma unroll
    for (int blk = 0; blk < 16; blk += 4) {
        {   float2 a = c[blk], b = c[blk+2];
            c[blk]   = make_float2(a.x + b.x, a.y + b.y);
            c[blk+2] = make_float2(a.x - b.x, a.y - b.y); }
        {   float2 a = c[blk+1], b = c[blk+3];
            float2 d = make_float2(a.x - b.x, a.y - b.y);
            c[blk+1] = make_float2(a.x + b.x, a.y + b.y);
            c[blk+3] = make_float2(d.y, -d.x); }
    }
#pragma unroll
    for (int blk = 0; blk < 16; blk += 2) {
        float2 a = c[blk], b = c[blk+1];
        c[blk]   = make_float2(a.x + b.x, a.y + b.y);
        c[blk+1] = make_float2(a.x - b.x, a.y - b.y);
    }
}

__device__ __forceinline__ void fft_reg_inv(float2* c) {
#pragma unroll
    for (int blk = 0; blk < 16; blk += 2) {
        float2 a = c[blk], b = c[blk+1];
        c[blk]   = make_float2(a.x + b.x, a.y + b.y);
        c[blk+1] = make_float2(a.x - b.x, a.y - b.y);
    }
#pragma unroll
    for (int blk = 0; blk < 16; blk += 4) {
        {   float2 a = c[blk], b = c[blk+2];
            c[blk]   = make_float2(a.x + b.x, a.y + b.y);
            c[blk+2] = make_float2(a.x - b.x, a.y - b.y); }
        {   float2 a = c[blk+1], b = c[blk+3];
            float2 bt = make_float2(-c[blk+3].y, c[blk+3].x);
            c[blk+1] = make_float2(a.x + bt.x, a.y + bt.y);
            c[blk+3] = make_float2(a.x - bt.x, a.y - bt.y); }
    }
    const float W8r[4] = {1.f, 0.70710678f, 0.f, -0.70710678f};
    const float W8i[4] = {0.f, 0.70710678f, 1.f, 0.70710678f};
#pragma unroll
    for (int blk = 0; blk < 16; blk += 8)
#pragma unroll
        for (int k = 0; k < 4; ++k) {
            float2 a = c[blk+k], b = c[blk+k+4];
            float2 bt = cmul(b, make_float2(W8r[k], W8i[k]));
            c[blk+k]   = make_float2(a.x + bt.x, a.y + bt.y);
            c[blk+k+4] = make_float2(a.x - bt.x, a.y - bt.y);
        }
    const float W16r[8] = {1.f, 0.92387953f, 0.70710678f, 0.38268343f,
                           0.f, -0.38268343f, -0.70710678f, -0.92387953f};
    const float W16i[8] = {0.f, 0.38268343f, 0.70710678f, 0.92387953f,
                           1.f, 0.92387953f, 0.70710678f, 0.38268343f};
#pragma unroll
    for (int k = 0; k < 8; ++k) {
        float2 a = c[k], b = c[k+8];
        float2 bt = cmul(b, make_float2(W16r[k], W16i[k]));
        c[k]   = make_float2(a.x + bt.x, a.y + bt.y);
        c[k+8] = make_float2(a.x - bt.x, a.y - bt.y);
    }
}

// ---------------------------------------------------------------------------
// K4a: kernel spectrum (scrambled, pre-scaled by 1/8192); h=4096 stage fused
// ---------------------------------------------------------------------------
__global__ __launch_bounds__(512) void k_kfft(
    const float* __restrict__ kf, float2* __restrict__ Kf)
{
    __shared__ float2 buf[8704];
    const int d = blockIdx.x, tid = threadIdx.x;
    const float* krow = kf + (size_t)d * LL;
    const float rinv0 = -FPI / 4096.f;
    for (int i = tid; i < 1024; i += 512) {
        float4 k4 = reinterpret_cast<const float4*>(krow)[i];
        int p = 4 * i;
        float kv[4] = {k4.x, k4.y, k4.z, k4.w};
#pragma unroll
        for (int q = 0; q < 4; ++q) {
            float sn, cs;
            __sincosf(rinv0 * (float)(p + q), &sn, &cs);
            buf[pidx(p + q)]        = make_float2(kv[q], 0.f);
            buf[pidx(p + q + 4096)] = make_float2(kv[q] * cs, kv[q] * sn);
        }
    }
    fft_lds_fwd(buf, tid);
    float2 c[16];
    const int p0 = tid * 16;
#pragma unroll
    for (int j = 0; j < 16; ++j) c[j] = buf[pidx(p0 + j)];
    fft_reg_fwd(c);
    float2* outp = Kf + (size_t)d * 8192 + p0;
#pragma unroll
    for (int j = 0; j < 16; ++j)
        outp[j] = make_float2(c[j].x * (1.f/8192.f), c[j].y * (1.f/8192.f));
}

// ---------------------------------------------------------------------------
// K4b: batch-folded fft conv: z = v[b=0] + i*v[b=1] (conv is linear, k real)
// -> y0 = Re(ifft), y1 = Im(ifft). + D*v skip + x0 gate, bf16 out per batch.
// ---------------------------------------------------------------------------
__global__ __launch_bounds__(512) void k_fftconv(
    const float* __restrict__ vin, const float2* __restrict__ Kf,
    const float* __restrict__ x0t, const float* __restrict__ Dp,
    ushort* __restrict__ yg)
{
    __shared__ float2 buf[8704];
    const int d = blockIdx.x, tid = threadIdx.x;
    const float* vrow0 = vin + (size_t)d * LL;
    const float* vrow1 = vin + ((size_t)DM + d) * LL;
    const float rinv0 = -FPI / 4096.f;
    for (int i = tid; i < 1024; i += 512) {
        float4 a4 = reinterpret_cast<const float4*>(vrow0)[i];
        float4 b4 = reinterpret_cast<const float4*>(vrow1)[i];
        int p = 4 * i;
        float ar[4] = {a4.x, a4.y, a4.z, a4.w};
        float br[4] = {b4.x, b4.y, b4.z, b4.w};
#pragma unroll
        for (int q = 0; q < 4; ++q) {
            float sn, cs;
            __sincosf(rinv0 * (float)(p + q), &sn, &cs);
            float2 z = make_float2(ar[q], br[q]);
            buf[pidx(p + q)]        = z;
            buf[pidx(p + q + 4096)] = cmul(z, make_float2(cs, sn));
        }
    }
    fft_lds_fwd(buf, tid);
    float2 c[16];
    const int p0 = tid * 16;
#pragma unroll
    for (int j = 0; j < 16; ++j) c[j] = buf[pidx(p0 + j)];
    fft_reg_fwd(c);
    const float2* kfr = Kf + (size_t)d * 8192 + p0;
#pragma unroll
    for (int j = 0; j < 16; ++j) c[j] = cmul(c[j], kfr[j]);
    fft_reg_inv(c);
#pragma unroll
    for (int j = 0; j < 16; ++j) buf[pidx(p0 + j)] = c[j];
    fft_lds_inv(buf, tid);
    const float Dd = Dp[d];
    const float* xrow0 = x0t + (size_t)d * LL;
    const float* xrow1 = x0t + ((size_t)DM + d) * LL;
    ushort* orow0 = yg + (size_t)d * LL;
    ushort* orow1 = yg + ((size_t)DM + d) * LL;
    for (int i = tid; i < 1024; i += 512) {
        float4 v0 = reinterpret_cast<const float4*>(vrow0)[i];
        float4 v1 = reinterpret_cast<const float4*>(vrow1)[i];
        float4 x0 = reinterpret_cast<const float4*>(xrow0)[i];
        float4 x1 = reinterpret_cast<const float4*>(xrow1)[i];
        int p = 4 * i;
        float2 y0 = buf[pidx(p+0)], y1 = buf[pidx(p+1)];
        float2 y2 = buf[pidx(p+2)], y3 = buf[pidx(p+3)];
        ushort4 s0, s1;
        s0.x = f2bf((y0.x + Dd * v0.x) * x0.x);
        s0.y = f2bf((y1.x + Dd * v0.y) * x0.y);
        s0.z = f2bf((y2.x + Dd * v0.z) * x0.z);
        s0.w = f2bf((y3.x + Dd * v0.w) * x0.w);
        s1.x = f2bf((y0.y + Dd * v1.x) * x1.x);
        s1.y = f2bf((y1.y + Dd * v1.y) * x1.y);
        s1.z = f2bf((y2.y + Dd * v1.z) * x1.z);
        s1.w = f2bf((y3.y + Dd * v1.w) * x1.w);
        *reinterpret_cast<ushort4*>(orow0 + p) = s0;
        *reinterpret_cast<ushort4*>(orow1 + p) = s1;
    }
}

// ---------------------------------------------------------------------------
// K_tr: yg[b][d][t] (bf16) -> Ag[b][t][d] (bf16), 64x64 LDS tiles
// ---------------------------------------------------------------------------
__global__ __launch_bounds__(256) void k_tr(
    const ushort* __restrict__ yg, ushort* __restrict__ Ag)
{
    __shared__ ushort S[64][72];
    const int b  = blockIdx.z;
    const int d0 = blockIdx.y * 64;
    const int t0 = blockIdx.x * 64;
    const int tid = threadIdx.x;
#pragma unroll
    for (int p = 0; p < 2; ++p) {
        int idx = p * 256 + tid;
        int dr = idx >> 3, c8 = (idx & 7) << 3;
        uint4 v = *reinterpret_cast<const uint4*>(
            yg + ((size_t)b * DM + d0 + dr) * LL + t0 + c8);
        *reinterpret_cast<uint4*>(&S[dr][c8]) = v;
    }
    __syncthreads();
#pragma unroll
    for (int p = 0; p < 2; ++p) {
        int idx = p * 256 + tid;
        int tr = idx >> 3, dq = (idx & 7) << 3;
        ushort tmp[8] __attribute__((aligned(16)));
#pragma unroll
        for (int q = 0; q < 8; ++q) tmp[q] = S[dq + q][tr];
        *reinterpret_cast<uint4*>(Ag + ((size_t)b * LL + t0 + tr) * DM + d0 + dq) =
            *reinterpret_cast<uint4*>(tmp);
    }
}

// ---------------------------------------------------------------------------
extern "C" void kernel_launch(void* const* d_in, const int* in_sizes, int n_in,
                              void* d_out, int out_size, void* d_ws, size_t ws_size,
                              hipStream_t stream)
{
    if (n_in < 17) return;
    const float* u    = (const float*)d_in[0];
    const float* w_in = (const float*)d_in[1];
    const float* b_in = (const float*)d_in[2];
    const float* sf_w = (const float*)d_in[3];
    const float* sf_b = (const float*)d_in[4];
    const float* z    = (const float*)d_in[5];
    const float* w0   = (const float*)d_in[6];
    const float* b0   = (const float*)d_in[7];
    const float* freq = (const float*)d_in[8];
    const float* w1   = (const float*)d_in[9];
    const float* b1   = (const float*)d_in[10];
    const float* w2   = (const float*)d_in[11];
    const float* b2   = (const float*)d_in[12];
    const float* wf   = (const float*)d_in[13];
    const float* Dp   = (const float*)d_in[14];
    const float* wout = (const float*)d_in[15];
    const float* bout = (const float*)d_in[16];
    float* out = (float*)d_out;
    float* ws  = (float*)d_ws;

    // Overlaid workspace (float offsets) — same layout as round 3.
    float*  up    = ws;
    float2* Kf    = (float2*)ws;
    float*  kfbuf = ws + 16777216;
    ushort* yg    = (ushort*)(ws + 16777216);
    float*  H3    = ws + 20971520;
    ushort* Ag    = (ushort*)(ws + 20971520);
    ushort* ub    = (ushort*)(ws + 25165824);
    float*  x0t   = ws + 25165824;
    ushort* wb    = (ushort*)(ws + 33554432);
    float*  vin   = ws + 33554432;
    ushort* woutb = (ushort*)(ws + 33554432);
    const size_t NEED = (size_t)41943040 * 4;
    if (ws_size < NEED) return;

    hipLaunchKernelGGL(k_cvt_bf16, dim3(2048), dim3(256), 0, stream, u, ub, 2097152);
    hipLaunchKernelGGL(k_cvt_bf16, dim3(2048), dim3(256), 0, stream, w_in, wb, 786432);
    hipLaunchKernelGGL(k_gemm_bf16, dim3(E3/128, 8192/128), dim3(256), 0, stream,
                       ub, wb, b_in, up, E3);
    hipLaunchKernelGGL(k_dwconv,   dim3(DM/32, LL/64, NB), dim3(256), 0, stream,
                       up, sf_w, sf_b, x0t, vin);
    hipLaunchKernelGGL(k_filt_mlp, dim3(LL/64), dim3(256), 0, stream,
                       z, w0, b0, freq, w1, b1, w2, b2, H3);
    hipLaunchKernelGGL(k_filt_k,   dim3(LL/64, DM/64), dim3(256), 0, stream,
                       H3, wf, kfbuf);
    hipLaunchKernelGGL(k_kfft,     dim3(DM), dim3(512), 0, stream,
                       kfbuf, Kf);
    hipLaunchKernelGGL(k_fftconv,  dim3(DM), dim3(512), 0, stream,
                       vin, Kf, x0t, Dp, yg);
    hipLaunchKernelGGL(k_cvt_bf16, dim3(1024), dim3(256), 0, stream, wout, woutb, 262144);
    hipLaunchKernelGGL(k_tr,       dim3(LL/64, DM/64, NB), dim3(256), 0, stream,
                       yg, Ag);
    hipLaunchKernelGGL(k_gemm_bf16, dim3(DM/128, 8192/128), dim3(256), 0, stream,
                       Ag, woutb, bout, out, DM);
}

// Round 5
// 287.538 us; speedup vs baseline: 6.5477x; 1.1184x over previous
//
#include <hip/hip_runtime.h>
#include <math.h>

#define DM   1024
#define LL   4096
#define NB   2
#define E3   3072
#define FPI  3.14159265358979323846f

typedef __bf16 bf16x8 __attribute__((ext_vector_type(8)));
typedef float  f32x4  __attribute__((ext_vector_type(4)));

__device__ __forceinline__ unsigned short f2bf(float x) {
    unsigned u = __float_as_uint(x);
    u += 0x7fffu + ((u >> 16) & 1u);
    return (unsigned short)(u >> 16);
}
__device__ __forceinline__ void gload16(void* lds, const void* g) {
    typedef const __attribute__((address_space(1))) unsigned int* gp_t;
    typedef __attribute__((address_space(3))) unsigned int* lp_t;
    __builtin_amdgcn_global_load_lds((gp_t)g, (lp_t)lds, 16, 0, 0);
}

// ---------------------------------------------------------------------------
// cvt: f32 -> bf16, vectorized x4
// ---------------------------------------------------------------------------
__global__ __launch_bounds__(256) void k_cvt_bf16(
    const float* __restrict__ in, ushort* __restrict__ out, int n4)
{
    int idx = blockIdx.x * 256 + threadIdx.x;
    int stride = gridDim.x * 256;
    for (int i = idx; i < n4; i += stride) {
        float4 v = reinterpret_cast<const float4*>(in)[i];
        ushort4 o;
        o.x = f2bf(v.x); o.y = f2bf(v.y); o.z = f2bf(v.z); o.w = f2bf(v.w);
        *reinterpret_cast<ushort4*>(out + 4 * i) = o;
    }
}

// ---------------------------------------------------------------------------
// MFMA bf16 GEMM: C[m][n] = sum_k A[m][k]*B[n][k] + bias[n]   (K=1024 fixed)
// ---------------------------------------------------------------------------
__global__ __launch_bounds__(256) void k_gemm_bf16(
    const ushort* __restrict__ A, const ushort* __restrict__ B,
    const float* __restrict__ bias, float* __restrict__ C, int ldc)
{
    __shared__ ushort As[128 * 32];
    __shared__ ushort Bs[128 * 32];
    const int tid  = threadIdx.x;
    const int lane = tid & 63;
    const int w    = tid >> 6;
    const int wm   = (w >> 1) << 6, wn = (w & 1) << 6;
    const int m0   = blockIdx.y << 7, n0 = blockIdx.x << 7;

    f32x4 acc[4][4];
#pragma unroll
    for (int i = 0; i < 4; ++i)
#pragma unroll
        for (int j = 0; j < 4; ++j)
#pragma unroll
            for (int r = 0; r < 4; ++r) acc[i][j][r] = 0.f;

    const char* Ab = (const char*)A + ((size_t)(m0 + (tid >> 2)) << 11) + ((tid & 3) << 4);
    const char* Bb = (const char*)B + ((size_t)(n0 + (tid >> 2)) << 11) + ((tid & 3) << 4);
    char* AsD = (char*)As + tid * 16;
    char* BsD = (char*)Bs + tid * 16;
    const char* ap = (const char*)As + ((wm + (lane & 15)) << 6) + ((lane >> 4) << 4);
    const char* bp = (const char*)Bs + ((wn + (lane & 15)) << 6) + ((lane >> 4) << 4);

    for (int k0 = 0; k0 < 1024; k0 += 32) {
        __syncthreads();
        gload16(AsD,        Ab + k0 * 2);
        gload16(AsD + 4096, Ab + 131072 + k0 * 2);
        gload16(BsD,        Bb + k0 * 2);
        gload16(BsD + 4096, Bb + 131072 + k0 * 2);
        __syncthreads();
        bf16x8 af[4], bfr[4];
#pragma unroll
        for (int i = 0; i < 4; ++i) {
            af[i]  = *(const bf16x8*)(ap + (i << 10));
            bfr[i] = *(const bf16x8*)(bp + (i << 10));
        }
#pragma unroll
        for (int i = 0; i < 4; ++i)
#pragma unroll
            for (int j = 0; j < 4; ++j)
                acc[i][j] = __builtin_amdgcn_mfma_f32_16x16x32_bf16(
                    af[i], bfr[j], acc[i][j], 0, 0, 0);
    }
    const int er = (lane >> 4) << 2;
    const int ec = lane & 15;
#pragma unroll
    for (int i = 0; i < 4; ++i) {
        int row = m0 + wm + (i << 4) + er;
#pragma unroll
        for (int j = 0; j < 4; ++j) {
            int col = n0 + wn + (j << 4) + ec;
            float bz = bias[col];
            float* cp = C + (size_t)row * ldc + col;
#pragma unroll
            for (int r = 0; r < 4; ++r)
                cp[(size_t)r * ldc] = acc[i][j][r] + bz;
        }
    }
}

// ---------------------------------------------------------------------------
// K2: depthwise conv3 + split + gate + transpose to [b][c][t]
// ---------------------------------------------------------------------------
__global__ __launch_bounds__(256) void k_dwconv(
    const float* __restrict__ up, const float* __restrict__ sfw,
    const float* __restrict__ sfb, float* __restrict__ x0t,
    float* __restrict__ vin)
{
    __shared__ float xT[32][65];
    __shared__ float vT[32][65];
    const int b  = blockIdx.z;
    const int t0 = blockIdx.y * 64;
    const int c0 = blockIdx.x * 32;
    const int tid = threadIdx.x;
    const int cL = tid & 31, tL = tid >> 5;
    const float* upb = up + (size_t)b * LL * E3;
    const int c = c0 + cL;

#pragma unroll
    for (int r = 0; r < 8; ++r) {
        int t_local = (r << 3) + tL;
        int t = t0 + t_local;
        float res[3];
#pragma unroll
        for (int s3 = 0; s3 < 3; ++s3) {
            int e = c + (s3 << 10);
            float w0 = sfw[e*3+0], w1 = sfw[e*3+1], w2 = sfw[e*3+2];
            float xa = (t >= 2) ? upb[(size_t)(t-2)*E3 + e] : 0.f;
            float xb = (t >= 1) ? upb[(size_t)(t-1)*E3 + e] : 0.f;
            float xc = upb[(size_t)t*E3 + e];
            res[s3] = w0*xa + w1*xb + w2*xc + sfb[e];
        }
        xT[cL][t_local] = res[0];
        vT[cL][t_local] = res[1] * res[2];
    }
    __syncthreads();
    const int cW = tid >> 3, q = tid & 7;
    float tmp[8];
#pragma unroll
    for (int i = 0; i < 8; ++i) tmp[i] = xT[cW][8*q + i];
    size_t off = ((size_t)b * DM + c0 + cW) * LL + t0 + 8*q;
    *reinterpret_cast<float4*>(x0t + off)     = make_float4(tmp[0], tmp[1], tmp[2], tmp[3]);
    *reinterpret_cast<float4*>(x0t + off + 4) = make_float4(tmp[4], tmp[5], tmp[6], tmp[7]);
#pragma unroll
    for (int i = 0; i < 8; ++i) tmp[i] = vT[cW][8*q + i];
    *reinterpret_cast<float4*>(vin + off)     = make_float4(tmp[0], tmp[1], tmp[2], tmp[3]);
    *reinterpret_cast<float4*>(vin + off + 4) = make_float4(tmp[4], tmp[5], tmp[6], tmp[7]);
}

// ---------------------------------------------------------------------------
// K3a: filter MLP
// ---------------------------------------------------------------------------
__global__ __launch_bounds__(256) void k_filt_mlp(
    const float* __restrict__ z, const float* __restrict__ w0,
    const float* __restrict__ b0, const float* __restrict__ fr,
    const float* __restrict__ w1, const float* __restrict__ b1,
    const float* __restrict__ w2, const float* __restrict__ b2,
    float* __restrict__ H3)
{
    __shared__ float w1t[64 * 65];
    __shared__ float w2t[64 * 65];
    __shared__ float hb[4][64];
    const int tid = threadIdx.x;
    for (int idx = tid; idx < 4096; idx += 256) {
        int j = idx >> 6, m = idx & 63;
        w1t[m*65 + j] = w1[idx];
        w2t[m*65 + j] = w2[idx];
    }
    __syncthreads();
    const int tl = tid >> 6, j = tid & 63;
    const float frj = fr[j];
    const float b0j = b0[j], b1j = b1[j], b2j = b2[j];
    const float w00 = w0[j*3+0], w01 = w0[j*3+1], w02 = w0[j*3+2];
    const int t0 = blockIdx.x * 64;
    for (int r = 0; r < 16; ++r) {
        int t = t0 + r*4 + tl;
        float z0 = z[t*3+0], z1 = z[t*3+1], z2 = z[t*3+2];
        float h = sinf(frj * (b0j + z0*w00 + z1*w01 + z2*w02));
        hb[tl][j] = h;
        __syncthreads();
        float s = b1j;
#pragma unroll
        for (int m = 0; m < 64; ++m) s = fmaf(hb[tl][m], w1t[m*65 + j], s);
        __syncthreads();
        h = sinf(frj * s);
        hb[tl][j] = h;
        __syncthreads();
        s = b2j;
#pragma unroll
        for (int m = 0; m < 64; ++m) s = fmaf(hb[tl][m], w2t[m*65 + j], s);
        h = sinf(frj * s);
        H3[(size_t)t * 64 + j] = h;
        __syncthreads();
    }
}

// ---------------------------------------------------------------------------
// K3b: kf[d][t] = (H3 @ wf^T) * exp-decay
// ---------------------------------------------------------------------------
__global__ __launch_bounds__(256) void k_filt_k(
    const float* __restrict__ H3, const float* __restrict__ wf,
    float* __restrict__ kf)
{
    __shared__ float Hs[64][65];
    __shared__ float Ws[64][65];
    const int tid = threadIdx.x;
    const int t0 = blockIdx.x * 64, d0 = blockIdx.y * 64;
    for (int idx = tid; idx < 4096; idx += 256) {
        int r = idx >> 6, cc = idx & 63;
        Hs[r][cc] = H3[(size_t)(t0 + r) * 64 + cc];
        Ws[r][cc] = wf[(size_t)(d0 + r) * 64 + cc];
    }
    __syncthreads();
    const int tx = tid & 15, ty = tid >> 4;
    float acc[4][4];
#pragma unroll
    for (int i = 0; i < 4; ++i)
#pragma unroll
        for (int jj = 0; jj < 4; ++jj) acc[i][jj] = 0.f;
#pragma unroll
    for (int j = 0; j < 64; ++j) {
        float wv[4], hv[4];
#pragma unroll
        for (int i = 0; i < 4; ++i) wv[i] = Ws[4*ty + i][j];
#pragma unroll
        for (int i = 0; i < 4; ++i) hv[i] = Hs[4*tx + i][j];
#pragma unroll
        for (int i = 0; i < 4; ++i)
#pragma unroll
            for (int jj = 0; jj < 4; ++jj) acc[i][jj] = fmaf(wv[i], hv[jj], acc[i][jj]);
    }
    const float mind = -3.0701134573253944f;
    const float maxd = -15.350567286626972f;
#pragma unroll
    for (int i = 0; i < 4; ++i) {
        int d = d0 + 4*ty + i;
        float delta = fabsf(mind + (maxd - mind) * ((float)d / 1023.f));
#pragma unroll
        for (int jj = 0; jj < 4; ++jj) {
            int t = t0 + 4*tx + jj;
            float tn = (float)t / 4095.f;
            kf[(size_t)d * LL + t] = acc[i][jj] * expf(-tn * delta);
        }
    }
}

// ---------------------------------------------------------------------------
// FFT helpers (8192-pt). Forward: fused radix-2 h=4096 in load, then 4
// radix-4 LDS stages (each = exact composition of two radix-2 DIF stages,
// so the scramble permutation is IDENTICAL to the radix-2 version), then
// 16-pt register FFT. Inverse mirrors exactly; final h=4096 radix-2 inverse
// stage is fused into the epilogue (upper half discarded).
// ---------------------------------------------------------------------------
__device__ __forceinline__ int pidx(int p) { return p + (p >> 4); }

__device__ __forceinline__ float2 cmul(float2 a, float2 b) {
    return make_float2(a.x*b.x - a.y*b.y, a.x*b.y + a.y*b.x);
}

__device__ void fft_lds_fwd4(float2* buf, int tid) {
    int lh = 10;
#pragma unroll
    for (int h = 2048; h >= 32; h >>= 2, lh -= 2) {
        const int hh = h >> 1;
        const float rinv = -FPI / (float)h;
        __syncthreads();
#pragma unroll
        for (int r = 0; r < 4; ++r) {
            int bf = (r << 9) + tid;             // 0..2047
            int q  = bf & (hh - 1);
            int g  = bf >> lh;
            int j  = (g << (lh + 2)) + q;        // g*2h + q
            float2 a = buf[pidx(j)];
            float2 b = buf[pidx(j + hh)];
            float2 c = buf[pidx(j + h)];
            float2 d = buf[pidx(j + h + hh)];
            float2 t0 = make_float2(a.x + c.x, a.y + c.y);
            float2 t1 = make_float2(a.x - c.x, a.y - c.y);
            float2 t2 = make_float2(b.x + d.x, b.y + d.y);
            float2 t3 = make_float2(b.y - d.y, d.x - b.x);   // -i*(b-d)
            float sn, cs;
            __sincosf(rinv * (float)q, &sn, &cs);             // W1
            float c2 = cs*cs - sn*sn, s2 = 2.f*cs*sn;         // W2 = W1^2
            float c3 = cs*c2 - sn*s2, s3 = cs*s2 + sn*c2;     // W3 = W1*W2
            buf[pidx(j)] = make_float2(t0.x + t2.x, t0.y + t2.y);
            float2 e1 = make_float2(t0.x - t2.x, t0.y - t2.y);
            buf[pidx(j + hh)] = make_float2(e1.x*c2 - e1.y*s2, e1.x*s2 + e1.y*c2);
            float2 e2 = make_float2(t1.x + t3.x, t1.y + t3.y);
            buf[pidx(j + h)] = make_float2(e2.x*cs - e2.y*sn, e2.x*sn + e2.y*cs);
            float2 e3 = make_float2(t1.x - t3.x, t1.y - t3.y);
            buf[pidx(j + h + hh)] = make_float2(e3.x*c3 - e3.y*s3, e3.x*s3 + e3.y*c3);
        }
    }
    __syncthreads();
}

__device__ void fft_lds_inv4(float2* buf, int tid) {
    int lh = 4;
#pragma unroll
    for (int h = 32; h <= 2048; h <<= 2, lh += 2) {
        const int hh = h >> 1;
        const float rpos = FPI / (float)h;
        __syncthreads();
#pragma unroll
        for (int r = 0; r < 4; ++r) {
            int bf = (r << 9) + tid;
            int q  = bf & (hh - 1);
            int g  = bf >> lh;
            int j  = (g << (lh + 2)) + q;
            float2 o0 = buf[pidx(j)];
            float2 o1 = buf[pidx(j + hh)];
            float2 o2 = buf[pidx(j + h)];
            float2 o3 = buf[pidx(j + h + hh)];
            float sn, cs;
            __sincosf(rpos * (float)q, &sn, &cs);             // conj(W1)
            float c2 = cs*cs - sn*sn, s2 = 2.f*cs*sn;         // conj(W2)
            float c3 = cs*c2 - sn*s2, s3 = cs*s2 + sn*c2;     // conj(W3)
            float2 p1 = make_float2(o1.x*c2 - o1.y*s2, o1.x*s2 + o1.y*c2);
            float2 p2 = make_float2(o2.x*cs - o2.y*sn, o2.x*sn + o2.y*cs);
            float2 p3 = make_float2(o3.x*c3 - o3.y*s3, o3.x*s3 + o3.y*c3);
            float2 u0 = make_float2(o0.x + p1.x, o0.y + p1.y);
            float2 u1 = make_float2(o0.x - p1.x, o0.y - p1.y);
            float2 u2 = make_float2(p2.x + p3.x, p2.y + p3.y);
            float2 u3 = make_float2(p2.x - p3.x, p2.y - p3.y);
            float2 ib = make_float2(-u3.y, u3.x);             // i*u3
            buf[pidx(j)]          = make_float2(u0.x + u2.x, u0.y + u2.y);
            buf[pidx(j + hh)]     = make_float2(u1.x + ib.x, u1.y + ib.y);
            buf[pidx(j + h)]      = make_float2(u0.x - u2.x, u0.y - u2.y);
            buf[pidx(j + h + hh)] = make_float2(u1.x - ib.x, u1.y - ib.y);
        }
    }
    __syncthreads();
}

__device__ __forceinline__ void fft_reg_fwd(float2* c) {
    const float W16r[8] = {1.f, 0.92387953f, 0.70710678f, 0.38268343f,
                           0.f, -0.38268343f, -0.70710678f, -0.92387953f};
    const float W16i[8] = {0.f, -0.38268343f, -0.70710678f, -0.92387953f,
                           -1.f, -0.92387953f, -0.70710678f, -0.38268343f};
#pragma unroll
    for (int k = 0; k < 8; ++k) {
        float2 a = c[k], b = c[k+8];
        float2 d = make_float2(a.x - b.x, a.y - b.y);
        c[k]   = make_float2(a.x + b.x, a.y + b.y);
        c[k+8] = cmul(d, make_float2(W16r[k], W16i[k]));
    }
    const float W8r[4] = {1.f, 0.70710678f, 0.f, -0.70710678f};
    const float W8i[4] = {0.f, -0.70710678f, -1.f, -0.70710678f};
#pragma unroll
    for (int blk = 0; blk < 16; blk += 8)
#pragma unroll
        for (int k = 0; k < 4; ++k) {
            float2 a = c[blk+k], b = c[blk+k+4];
            float2 d = make_float2(a.x - b.x, a.y - b.y);
            c[blk+k]   = make_float2(a.x + b.x, a.y + b.y);
            c[blk+k+4] = cmul(d, make_float2(W8r[k], W8i[k]));
        }
#pragma unroll
    for (int blk = 0; blk < 16; blk += 4) {
        {   float2 a = c[blk], b = c[blk+2];
            c[blk]   = make_float2(a.x + b.x, a.y + b.y);
            c[blk+2] = make_float2(a.x - b.x, a.y - b.y); }
        {   float2 a = c[blk+1], b = c[blk+3];
            float2 d = make_float2(a.x - b.x, a.y - b.y);
            c[blk+1] = make_float2(a.x + b.x, a.y + b.y);
            c[blk+3] = make_float2(d.y, -d.x); }
    }
#pragma unroll
    for (int blk = 0; blk < 16; blk += 2) {
        float2 a = c[blk], b = c[blk+1];
        c[blk]   = make_float2(a.x + b.x, a.y + b.y);
        c[blk+1] = make_float2(a.x - b.x, a.y - b.y);
    }
}

__device__ __forceinline__ void fft_reg_inv(float2* c) {
#pragma unroll
    for (int blk = 0; blk < 16; blk += 2) {
        float2 a = c[blk], b = c[blk+1];
        c[blk]   = make_float2(a.x + b.x, a.y + b.y);
        c[blk+1] = make_float2(a.x - b.x, a.y - b.y);
    }
#pragma unroll
    for (int blk = 0; blk < 16; blk += 4) {
        {   float2 a = c[blk], b = c[blk+2];
            c[blk]   = make_float2(a.x + b.x, a.y + b.y);
            c[blk+2] = make_float2(a.x - b.x, a.y - b.y); }
        {   float2 a = c[blk+1], b = c[blk+3];
            float2 bt = make_float2(-c[blk+3].y, c[blk+3].x);
            c[blk+1] = make_float2(a.x + bt.x, a.y + bt.y);
            c[blk+3] = make_float2(a.x - bt.x, a.y - bt.y); }
    }
    const float W8r[4] = {1.f, 0.70710678f, 0.f, -0.70710678f};
    const float W8i[4] = {0.f, 0.70710678f, 1.f, 0.70710678f};
#pragma unroll
    for (int blk = 0; blk < 16; blk += 8)
#pragma unroll
        for (int k = 0; k < 4; ++k) {
            float2 a = c[blk+k], b = c[blk+k+4];
            float2 bt = cmul(b, make_float2(W8r[k], W8i[k]));
            c[blk+k]   = make_float2(a.x + bt.x, a.y + bt.y);
            c[blk+k+4] = make_float2(a.x - bt.x, a.y - bt.y);
        }
    const float W16r[8] = {1.f, 0.92387953f, 0.70710678f, 0.38268343f,
                           0.f, -0.38268343f, -0.70710678f, -0.92387953f};
    const float W16i[8] = {0.f, 0.38268343f, 0.70710678f, 0.92387953f,
                           1.f, 0.92387953f, 0.70710678f, 0.38268343f};
#pragma unroll
    for (int k = 0; k < 8; ++k) {
        float2 a = c[k], b = c[k+8];
        float2 bt = cmul(b, make_float2(W16r[k], W16i[k]));
        c[k]   = make_float2(a.x + bt.x, a.y + bt.y);
        c[k+8] = make_float2(a.x - bt.x, a.y - bt.y);
    }
}

// ---------------------------------------------------------------------------
// K4a: kernel spectrum (scrambled, pre-scaled by 1/8192); h=4096 stage fused
// ---------------------------------------------------------------------------
__global__ __launch_bounds__(512) void k_kfft(
    const float* __restrict__ kf, float2* __restrict__ Kf)
{
    __shared__ float2 buf[8704];
    const int d = blockIdx.x, tid = threadIdx.x;
    const float* krow = kf + (size_t)d * LL;
    const float rinv0 = -FPI / 4096.f;
    for (int i = tid; i < 1024; i += 512) {
        float4 k4 = reinterpret_cast<const float4*>(krow)[i];
        int p = 4 * i;
        float kv[4] = {k4.x, k4.y, k4.z, k4.w};
#pragma unroll
        for (int q = 0; q < 4; ++q) {
            float sn, cs;
            __sincosf(rinv0 * (float)(p + q), &sn, &cs);
            buf[pidx(p + q)]        = make_float2(kv[q], 0.f);
            buf[pidx(p + q + 4096)] = make_float2(kv[q] * cs, kv[q] * sn);
        }
    }
    fft_lds_fwd4(buf, tid);
    float2 c[16];
    const int p0 = tid * 16;
#pragma unroll
    for (int j = 0; j < 16; ++j) c[j] = buf[pidx(p0 + j)];
    fft_reg_fwd(c);
    float2* outp = Kf + (size_t)d * 8192 + p0;
#pragma unroll
    for (int j = 0; j < 16; ++j)
        outp[j] = make_float2(c[j].x * (1.f/8192.f), c[j].y * (1.f/8192.f));
}

// ---------------------------------------------------------------------------
// K4b: batch-folded fft conv: z = v[b=0] + i*v[b=1]; final inverse h=4096
// stage fused into the epilogue. + D*v skip + x0 gate, bf16 out per batch.
// ---------------------------------------------------------------------------
__global__ __launch_bounds__(512) void k_fftconv(
    const float* __restrict__ vin, const float2* __restrict__ Kf,
    const float* __restrict__ x0t, const float* __restrict__ Dp,
    ushort* __restrict__ yg)
{
    __shared__ float2 buf[8704];
    const int d = blockIdx.x, tid = threadIdx.x;
    const float* vrow0 = vin + (size_t)d * LL;
    const float* vrow1 = vin + ((size_t)DM + d) * LL;
    const float rinv0 = -FPI / 4096.f;
    for (int i = tid; i < 1024; i += 512) {
        float4 a4 = reinterpret_cast<const float4*>(vrow0)[i];
        float4 b4 = reinterpret_cast<const float4*>(vrow1)[i];
        int p = 4 * i;
        float ar[4] = {a4.x, a4.y, a4.z, a4.w};
        float br[4] = {b4.x, b4.y, b4.z, b4.w};
#pragma unroll
        for (int q = 0; q < 4; ++q) {
            float sn, cs;
            __sincosf(rinv0 * (float)(p + q), &sn, &cs);
            float2 z = make_float2(ar[q], br[q]);
            buf[pidx(p + q)]        = z;
            buf[pidx(p + q + 4096)] = cmul(z, make_float2(cs, sn));
        }
    }
    fft_lds_fwd4(buf, tid);
    float2 c[16];
    const int p0 = tid * 16;
#pragma unroll
    for (int j = 0; j < 16; ++j) c[j] = buf[pidx(p0 + j)];
    fft_reg_fwd(c);
    const float2* kfr = Kf + (size_t)d * 8192 + p0;
#pragma unroll
    for (int j = 0; j < 16; ++j) c[j] = cmul(c[j], kfr[j]);
    fft_reg_inv(c);
#pragma unroll
    for (int j = 0; j < 16; ++j) buf[pidx(p0 + j)] = c[j];
    fft_lds_inv4(buf, tid);
    const float Dd = Dp[d];
    const float* xrow0 = x0t + (size_t)d * LL;
    const float* xrow1 = x0t + ((size_t)DM + d) * LL;
    ushort* orow0 = yg + (size_t)d * LL;
    ushort* orow1 = yg + ((size_t)DM + d) * LL;
    const float rinv4 = FPI / 4096.f;
    for (int i = tid; i < 1024; i += 512) {
        float4 v0 = reinterpret_cast<const float4*>(vrow0)[i];
        float4 v1 = reinterpret_cast<const float4*>(vrow1)[i];
        float4 x0 = reinterpret_cast<const float4*>(xrow0)[i];
        float4 x1 = reinterpret_cast<const float4*>(xrow1)[i];
        int p = 4 * i;
        float vr0[4] = {v0.x, v0.y, v0.z, v0.w};
        float vr1[4] = {v1.x, v1.y, v1.z, v1.w};
        float xr0[4] = {x0.x, x0.y, x0.z, x0.w};
        float xr1[4] = {x1.x, x1.y, x1.z, x1.w};
        ushort s0[4], s1[4];
#pragma unroll
        for (int q = 0; q < 4; ++q) {
            // fused final inverse radix-2 stage (h=4096), lower half only
            float sn, cs;
            __sincosf(rinv4 * (float)(p + q), &sn, &cs);
            float2 a  = buf[pidx(p + q)];
            float2 bb = buf[pidx(p + q + 4096)];
            float2 bt = cmul(bb, make_float2(cs, sn));
            float yre = a.x + bt.x;   // batch 0
            float yim = a.y + bt.y;   // batch 1
            s0[q] = f2bf((yre + Dd * vr0[q]) * xr0[q]);
            s1[q] = f2bf((yim + Dd * vr1[q]) * xr1[q]);
        }
        *reinterpret_cast<ushort4*>(orow0 + p) = make_ushort4(s0[0], s0[1], s0[2], s0[3]);
        *reinterpret_cast<ushort4*>(orow1 + p) = make_ushort4(s1[0], s1[1], s1[2], s1[3]);
    }
}

// ---------------------------------------------------------------------------
// K_tr: yg[b][d][t] (bf16) -> Ag[b][t][d] (bf16), 64x64 LDS tiles
// ---------------------------------------------------------------------------
__global__ __launch_bounds__(256) void k_tr(
    const ushort* __restrict__ yg, ushort* __restrict__ Ag)
{
    __shared__ ushort S[64][72];
    const int b  = blockIdx.z;
    const int d0 = blockIdx.y * 64;
    const int t0 = blockIdx.x * 64;
    const int tid = threadIdx.x;
#pragma unroll
    for (int p = 0; p < 2; ++p) {
        int idx = p * 256 + tid;
        int dr = idx >> 3, c8 = (idx & 7) << 3;
        uint4 v = *reinterpret_cast<const uint4*>(
            yg + ((size_t)b * DM + d0 + dr) * LL + t0 + c8);
        *reinterpret_cast<uint4*>(&S[dr][c8]) = v;
    }
    __syncthreads();
#pragma unroll
    for (int p = 0; p < 2; ++p) {
        int idx = p * 256 + tid;
        int tr = idx >> 3, dq = (idx & 7) << 3;
        ushort tmp[8] __attribute__((aligned(16)));
#pragma unroll
        for (int q = 0; q < 8; ++q) tmp[q] = S[dq + q][tr];
        *reinterpret_cast<uint4*>(Ag + ((size_t)b * LL + t0 + tr) * DM + d0 + dq) =
            *reinterpret_cast<uint4*>(tmp);
    }
}

// ---------------------------------------------------------------------------
extern "C" void kernel_launch(void* const* d_in, const int* in_sizes, int n_in,
                              void* d_out, int out_size, void* d_ws, size_t ws_size,
                              hipStream_t stream)
{
    if (n_in < 17) return;
    const float* u    = (const float*)d_in[0];
    const float* w_in = (const float*)d_in[1];
    const float* b_in = (const float*)d_in[2];
    const float* sf_w = (const float*)d_in[3];
    const float* sf_b = (const float*)d_in[4];
    const float* z    = (const float*)d_in[5];
    const float* w0   = (const float*)d_in[6];
    const float* b0   = (const float*)d_in[7];
    const float* freq = (const float*)d_in[8];
    const float* w1   = (const float*)d_in[9];
    const float* b1   = (const float*)d_in[10];
    const float* w2   = (const float*)d_in[11];
    const float* b2   = (const float*)d_in[12];
    const float* wf   = (const float*)d_in[13];
    const float* Dp   = (const float*)d_in[14];
    const float* wout = (const float*)d_in[15];
    const float* bout = (const float*)d_in[16];
    float* out = (float*)d_out;
    float* ws  = (float*)d_ws;

    // Overlaid workspace (float offsets) — same layout as round 3.
    float*  up    = ws;
    float2* Kf    = (float2*)ws;
    float*  kfbuf = ws + 16777216;
    ushort* yg    = (ushort*)(ws + 16777216);
    float*  H3    = ws + 20971520;
    ushort* Ag    = (ushort*)(ws + 20971520);
    ushort* ub    = (ushort*)(ws + 25165824);
    float*  x0t   = ws + 25165824;
    ushort* wb    = (ushort*)(ws + 33554432);
    float*  vin   = ws + 33554432;
    ushort* woutb = (ushort*)(ws + 33554432);
    const size_t NEED = (size_t)41943040 * 4;
    if (ws_size < NEED) return;

    hipLaunchKernelGGL(k_cvt_bf16, dim3(2048), dim3(256), 0, stream, u, ub, 2097152);
    hipLaunchKernelGGL(k_cvt_bf16, dim3(2048), dim3(256), 0, stream, w_in, wb, 786432);
    hipLaunchKernelGGL(k_gemm_bf16, dim3(E3/128, 8192/128), dim3(256), 0, stream,
                       ub, wb, b_in, up, E3);
    hipLaunchKernelGGL(k_dwconv,   dim3(DM/32, LL/64, NB), dim3(256), 0, stream,
                       up, sf_w, sf_b, x0t, vin);
    hipLaunchKernelGGL(k_filt_mlp, dim3(LL/64), dim3(256), 0, stream,
                       z, w0, b0, freq, w1, b1, w2, b2, H3);
    hipLaunchKernelGGL(k_filt_k,   dim3(LL/64, DM/64), dim3(256), 0, stream,
                       H3, wf, kfbuf);
    hipLaunchKernelGGL(k_kfft,     dim3(DM), dim3(512), 0, stream,
                       kfbuf, Kf);
    hipLaunchKernelGGL(k_fftconv,  dim3(DM), dim3(512), 0, stream,
                       vin, Kf, x0t, Dp, yg);
    hipLaunchKernelGGL(k_cvt_bf16, dim3(1024), dim3(256), 0, stream, wout, woutb, 262144);
    hipLaunchKernelGGL(k_tr,       dim3(LL/64, DM/64, NB), dim3(256), 0, stream,
                       yg, Ag);
    hipLaunchKernelGGL(k_gemm_bf16, dim3(DM/128, 8192/128), dim3(256), 0, stream,
                       Ag, woutb, bout, out, DM);
}

// Round 6
// 267.484 us; speedup vs baseline: 7.0386x; 1.0750x over previous
//
#include <hip/hip_runtime.h>
#include <math.h>

#define DM   1024
#define LL   4096
#define NB   2
#define E3   3072
#define FPI  3.14159265358979323846f

typedef __bf16 bf16x8 __attribute__((ext_vector_type(8)));
typedef float  f32x4  __attribute__((ext_vector_type(4)));
typedef _Float16 f16x2 __attribute__((ext_vector_type(2)));

__device__ __forceinline__ unsigned short f2bf(float x) {
    unsigned u = __float_as_uint(x);
    u += 0x7fffu + ((u >> 16) & 1u);
    return (unsigned short)(u >> 16);
}
__device__ __forceinline__ void gload16(void* lds, const void* g) {
    typedef const __attribute__((address_space(1))) unsigned int* gp_t;
    typedef __attribute__((address_space(3))) unsigned int* lp_t;
    __builtin_amdgcn_global_load_lds((gp_t)g, (lp_t)lds, 16, 0, 0);
}

// ---------------------------------------------------------------------------
// cvt: f32 -> bf16, vectorized x4
// ---------------------------------------------------------------------------
__global__ __launch_bounds__(256) void k_cvt_bf16(
    const float* __restrict__ in, ushort* __restrict__ out, int n4)
{
    int idx = blockIdx.x * 256 + threadIdx.x;
    int stride = gridDim.x * 256;
    for (int i = idx; i < n4; i += stride) {
        float4 v = reinterpret_cast<const float4*>(in)[i];
        ushort4 o;
        o.x = f2bf(v.x); o.y = f2bf(v.y); o.z = f2bf(v.z); o.w = f2bf(v.w);
        *reinterpret_cast<ushort4*>(out + 4 * i) = o;
    }
}

// ---------------------------------------------------------------------------
// 256x256 8-phase bf16 MFMA GEMM (K=1024): C = A@B^T + bias
// 512 thr (8 waves 2Mx4N), BK=64, LDS 128KB = 2buf x {A-k0,A-k1,B-k0,B-k1}
// halves (256x32 bf16). Counted vmcnt(4), raw barriers, setprio, src-side
// LDS swizzle (chunk ^= (row>>1)&3).
// ---------------------------------------------------------------------------
__global__ __launch_bounds__(512, 2) void k_gemm256(
    const ushort* __restrict__ A, const ushort* __restrict__ B,
    const float* __restrict__ bias, float* __restrict__ C,
    int Ntiles, int ldc)
{
    __shared__ __align__(16) char ldsm[131072];
    const int tid  = threadIdx.x;
    const int lane = tid & 63;
    const int w    = tid >> 6;
    const int wr   = w >> 2, wc = w & 3;

    // XCD-aware bijective swizzle (gridDim.x % 8 == 0)
    const int cpx = gridDim.x >> 3;
    int swz = (blockIdx.x & 7) * cpx + (blockIdx.x >> 3);
    const int m0 = (swz / Ntiles) << 8;
    const int n0 = (swz % Ntiles) << 8;

    // staging source (per-thread, pre-swizzled): row r0 = tid>>2, chunk tid&3
    const int r0 = tid >> 2;
    const int swzc = ((tid & 3) ^ ((r0 >> 1) & 3)) << 4;
    const char* Asrc = (const char*)A + ((size_t)(m0 + r0) << 11) + swzc;
    const char* Bsrc = (const char*)B + ((size_t)(n0 + r0) << 11) + swzc;
    char* Ld = ldsm + tid * 16;

    // ds_read bases (bytes, within buffer): A half at 0/+16384, B at 32768/+16384
    const int lm = lane & 15, lk = lane >> 4;
    const int rA = wr * 128 + lm;
    const int rB = wc * 64 + lm;
    const int aBase = rA * 64 + ((lk ^ ((rA >> 1) & 3)) << 4);
    const int bBase = 32768 + rB * 64 + ((lk ^ ((rB >> 1) & 3)) << 4);

#define STG_A(ks, nb, t1) do { \
    gload16(Ld + (nb) + (ks)*16384,        Asrc + (t1)*128 + (ks)*64); \
    gload16(Ld + (nb) + (ks)*16384 + 8192, Asrc + (t1)*128 + (ks)*64 + 262144); } while(0)
#define STG_B(ks, nb, t1) do { \
    gload16(Ld + (nb) + 32768 + (ks)*16384,        Bsrc + (t1)*128 + (ks)*64); \
    gload16(Ld + (nb) + 32768 + (ks)*16384 + 8192, Bsrc + (t1)*128 + (ks)*64 + 262144); } while(0)
#define LDA(buf, ks, m) (*(const bf16x8*)(ldsm + (buf) + (ks)*16384 + aBase + (m)*1024))
#define LDB(buf, ks, n) (*(const bf16x8*)(ldsm + (buf) + (ks)*16384 + bBase + (n)*1024))
#define VMCNT4() asm volatile("s_waitcnt vmcnt(4)" ::: "memory")
#define VMCNT0() asm volatile("s_waitcnt vmcnt(0)" ::: "memory")
#define BAR() __builtin_amdgcn_s_barrier()

    f32x4 acc[8][4];
#pragma unroll
    for (int i = 0; i < 8; ++i)
#pragma unroll
        for (int j = 0; j < 4; ++j)
#pragma unroll
            for (int r = 0; r < 4; ++r) acc[i][j][r] = 0.f;

    // prologue: stage tile 0 (order A-k0, B-k0, A-k1, B-k1)
    STG_A(0, 0, 0); STG_B(0, 0, 0); STG_A(1, 0, 0); STG_B(1, 0, 0);
    VMCNT4();
    BAR();

    bf16x8 af[4], bq[4];
#pragma unroll 1
    for (int t = 0; t < 15; ++t) {
        const int buf = (t & 1) << 16;
        const int nb  = ((t + 1) & 1) << 16;
        const int t1  = t + 1;
        // ph1: B-k0 + A-k0[M0-3]; stage A-k0(t+1)
#pragma unroll
        for (int n = 0; n < 4; ++n) bq[n] = LDB(buf, 0, n);
#pragma unroll
        for (int m = 0; m < 4; ++m) af[m] = LDA(buf, 0, m);
        STG_A(0, nb, t1);
        BAR();
        __builtin_amdgcn_s_setprio(1);
#pragma unroll
        for (int m = 0; m < 4; ++m)
#pragma unroll
            for (int n = 0; n < 4; ++n)
                acc[m][n] = __builtin_amdgcn_mfma_f32_16x16x32_bf16(af[m], bq[n], acc[m][n], 0, 0, 0);
        __builtin_amdgcn_s_setprio(0);
        BAR();
        // ph2: A-k0[M4-7]; stage B-k0(t+1); vmcnt(4)
#pragma unroll
        for (int m = 0; m < 4; ++m) af[m] = LDA(buf, 0, 4 + m);
        STG_B(0, nb, t1);
        VMCNT4();
        BAR();
        __builtin_amdgcn_s_setprio(1);
#pragma unroll
        for (int m = 0; m < 4; ++m)
#pragma unroll
            for (int n = 0; n < 4; ++n)
                acc[4 + m][n] = __builtin_amdgcn_mfma_f32_16x16x32_bf16(af[m], bq[n], acc[4 + m][n], 0, 0, 0);
        __builtin_amdgcn_s_setprio(0);
        BAR();
        // ph3: B-k1 + A-k1[M0-3]; stage A-k1(t+1)
#pragma unroll
        for (int n = 0; n < 4; ++n) bq[n] = LDB(buf, 1, n);
#pragma unroll
        for (int m = 0; m < 4; ++m) af[m] = LDA(buf, 1, m);
        STG_A(1, nb, t1);
        BAR();
        __builtin_amdgcn_s_setprio(1);
#pragma unroll
        for (int m = 0; m < 4; ++m)
#pragma unroll
            for (int n = 0; n < 4; ++n)
                acc[m][n] = __builtin_amdgcn_mfma_f32_16x16x32_bf16(af[m], bq[n], acc[m][n], 0, 0, 0);
        __builtin_amdgcn_s_setprio(0);
        BAR();
        // ph4: A-k1[M4-7]; stage B-k1(t+1); vmcnt(4)
#pragma unroll
        for (int m = 0; m < 4; ++m) af[m] = LDA(buf, 1, 4 + m);
        STG_B(1, nb, t1);
        VMCNT4();
        BAR();
        __builtin_amdgcn_s_setprio(1);
#pragma unroll
        for (int m = 0; m < 4; ++m)
#pragma unroll
            for (int n = 0; n < 4; ++n)
                acc[4 + m][n] = __builtin_amdgcn_mfma_f32_16x16x32_bf16(af[m], bq[n], acc[4 + m][n], 0, 0, 0);
        __builtin_amdgcn_s_setprio(0);
        BAR();
    }
    {   // peeled t = 15 (no staging)
        const int buf = 1 << 16;
#pragma unroll
        for (int n = 0; n < 4; ++n) bq[n] = LDB(buf, 0, n);
#pragma unroll
        for (int m = 0; m < 4; ++m) af[m] = LDA(buf, 0, m);
        BAR();
#pragma unroll
        for (int m = 0; m < 4; ++m)
#pragma unroll
            for (int n = 0; n < 4; ++n)
                acc[m][n] = __builtin_amdgcn_mfma_f32_16x16x32_bf16(af[m], bq[n], acc[m][n], 0, 0, 0);
        BAR();
#pragma unroll
        for (int m = 0; m < 4; ++m) af[m] = LDA(buf, 0, 4 + m);
        VMCNT0();
        BAR();
#pragma unroll
        for (int m = 0; m < 4; ++m)
#pragma unroll
            for (int n = 0; n < 4; ++n)
                acc[4 + m][n] = __builtin_amdgcn_mfma_f32_16x16x32_bf16(af[m], bq[n], acc[4 + m][n], 0, 0, 0);
        BAR();
#pragma unroll
        for (int n = 0; n < 4; ++n) bq[n] = LDB(buf, 1, n);
#pragma unroll
        for (int m = 0; m < 4; ++m) af[m] = LDA(buf, 1, m);
        BAR();
#pragma unroll
        for (int m = 0; m < 4; ++m)
#pragma unroll
            for (int n = 0; n < 4; ++n)
                acc[m][n] = __builtin_amdgcn_mfma_f32_16x16x32_bf16(af[m], bq[n], acc[m][n], 0, 0, 0);
        BAR();
#pragma unroll
        for (int m = 0; m < 4; ++m) af[m] = LDA(buf, 1, 4 + m);
        BAR();
#pragma unroll
        for (int m = 0; m < 4; ++m)
#pragma unroll
            for (int n = 0; n < 4; ++n)
                acc[4 + m][n] = __builtin_amdgcn_mfma_f32_16x16x32_bf16(af[m], bq[n], acc[4 + m][n], 0, 0, 0);
    }
    // epilogue
    const int er = lk << 2, ec = lm;
#pragma unroll
    for (int m = 0; m < 8; ++m) {
        int row = m0 + wr * 128 + m * 16 + er;
#pragma unroll
        for (int n = 0; n < 4; ++n) {
            int col = n0 + wc * 64 + n * 16 + ec;
            float bz = bias[col];
            float* cp = C + (size_t)row * ldc + col;
#pragma unroll
            for (int r = 0; r < 4; ++r)
                cp[(size_t)r * ldc] = acc[m][n][r] + bz;
        }
    }
#undef STG_A
#undef STG_B
#undef LDA
#undef LDB
#undef VMCNT4
#undef VMCNT0
#undef BAR
}

// ---------------------------------------------------------------------------
// 128x128 m97-structure MFMA GEMM (kept for the out-projection)
// ---------------------------------------------------------------------------
__global__ __launch_bounds__(256) void k_gemm_bf16(
    const ushort* __restrict__ A, const ushort* __restrict__ B,
    const float* __restrict__ bias, float* __restrict__ C, int ldc)
{
    __shared__ ushort As[128 * 32];
    __shared__ ushort Bs[128 * 32];
    const int tid  = threadIdx.x;
    const int lane = tid & 63;
    const int w    = tid >> 6;
    const int wm   = (w >> 1) << 6, wn = (w & 1) << 6;
    const int m0   = blockIdx.y << 7, n0 = blockIdx.x << 7;

    f32x4 acc[4][4];
#pragma unroll
    for (int i = 0; i < 4; ++i)
#pragma unroll
        for (int j = 0; j < 4; ++j)
#pragma unroll
            for (int r = 0; r < 4; ++r) acc[i][j][r] = 0.f;

    const char* Ab = (const char*)A + ((size_t)(m0 + (tid >> 2)) << 11) + ((tid & 3) << 4);
    const char* Bb = (const char*)B + ((size_t)(n0 + (tid >> 2)) << 11) + ((tid & 3) << 4);
    char* AsD = (char*)As + tid * 16;
    char* BsD = (char*)Bs + tid * 16;
    const char* ap = (const char*)As + ((wm + (lane & 15)) << 6) + ((lane >> 4) << 4);
    const char* bp = (const char*)Bs + ((wn + (lane & 15)) << 6) + ((lane >> 4) << 4);

    for (int k0 = 0; k0 < 1024; k0 += 32) {
        __syncthreads();
        gload16(AsD,        Ab + k0 * 2);
        gload16(AsD + 4096, Ab + 131072 + k0 * 2);
        gload16(BsD,        Bb + k0 * 2);
        gload16(BsD + 4096, Bb + 131072 + k0 * 2);
        __syncthreads();
        bf16x8 af[4], bfr[4];
#pragma unroll
        for (int i = 0; i < 4; ++i) {
            af[i]  = *(const bf16x8*)(ap + (i << 10));
            bfr[i] = *(const bf16x8*)(bp + (i << 10));
        }
#pragma unroll
        for (int i = 0; i < 4; ++i)
#pragma unroll
            for (int j = 0; j < 4; ++j)
                acc[i][j] = __builtin_amdgcn_mfma_f32_16x16x32_bf16(
                    af[i], bfr[j], acc[i][j], 0, 0, 0);
    }
    const int er = (lane >> 4) << 2;
    const int ec = lane & 15;
#pragma unroll
    for (int i = 0; i < 4; ++i) {
        int row = m0 + wm + (i << 4) + er;
#pragma unroll
        for (int j = 0; j < 4; ++j) {
            int col = n0 + wn + (j << 4) + ec;
            float bz = bias[col];
            float* cp = C + (size_t)row * ldc + col;
#pragma unroll
            for (int r = 0; r < 4; ++r)
                cp[(size_t)r * ldc] = acc[i][j][r] + bz;
        }
    }
}

// ---------------------------------------------------------------------------
// K2: depthwise conv3 + split + gate + transpose to [b][c][t]
// ---------------------------------------------------------------------------
__global__ __launch_bounds__(256) void k_dwconv(
    const float* __restrict__ up, const float* __restrict__ sfw,
    const float* __restrict__ sfb, float* __restrict__ x0t,
    float* __restrict__ vin)
{
    __shared__ float xT[32][65];
    __shared__ float vT[32][65];
    const int b  = blockIdx.z;
    const int t0 = blockIdx.y * 64;
    const int c0 = blockIdx.x * 32;
    const int tid = threadIdx.x;
    const int cL = tid & 31, tL = tid >> 5;
    const float* upb = up + (size_t)b * LL * E3;
    const int c = c0 + cL;

#pragma unroll
    for (int r = 0; r < 8; ++r) {
        int t_local = (r << 3) + tL;
        int t = t0 + t_local;
        float res[3];
#pragma unroll
        for (int s3 = 0; s3 < 3; ++s3) {
            int e = c + (s3 << 10);
            float w0 = sfw[e*3+0], w1 = sfw[e*3+1], w2 = sfw[e*3+2];
            float xa = (t >= 2) ? upb[(size_t)(t-2)*E3 + e] : 0.f;
            float xb = (t >= 1) ? upb[(size_t)(t-1)*E3 + e] : 0.f;
            float xc = upb[(size_t)t*E3 + e];
            res[s3] = w0*xa + w1*xb + w2*xc + sfb[e];
        }
        xT[cL][t_local] = res[0];
        vT[cL][t_local] = res[1] * res[2];
    }
    __syncthreads();
    const int cW = tid >> 3, q = tid & 7;
    float tmp[8];
#pragma unroll
    for (int i = 0; i < 8; ++i) tmp[i] = xT[cW][8*q + i];
    size_t off = ((size_t)b * DM + c0 + cW) * LL + t0 + 8*q;
    *reinterpret_cast<float4*>(x0t + off)     = make_float4(tmp[0], tmp[1], tmp[2], tmp[3]);
    *reinterpret_cast<float4*>(x0t + off + 4) = make_float4(tmp[4], tmp[5], tmp[6], tmp[7]);
#pragma unroll
    for (int i = 0; i < 8; ++i) tmp[i] = vT[cW][8*q + i];
    *reinterpret_cast<float4*>(vin + off)     = make_float4(tmp[0], tmp[1], tmp[2], tmp[3]);
    *reinterpret_cast<float4*>(vin + off + 4) = make_float4(tmp[4], tmp[5], tmp[6], tmp[7]);
}

// ---------------------------------------------------------------------------
// K3a: filter MLP
// ---------------------------------------------------------------------------
__global__ __launch_bounds__(256) void k_filt_mlp(
    const float* __restrict__ z, const float* __restrict__ w0,
    const float* __restrict__ b0, const float* __restrict__ fr,
    const float* __restrict__ w1, const float* __restrict__ b1,
    const float* __restrict__ w2, const float* __restrict__ b2,
    float* __restrict__ H3)
{
    __shared__ float w1t[64 * 65];
    __shared__ float w2t[64 * 65];
    __shared__ float hb[4][64];
    const int tid = threadIdx.x;
    for (int idx = tid; idx < 4096; idx += 256) {
        int j = idx >> 6, m = idx & 63;
        w1t[m*65 + j] = w1[idx];
        w2t[m*65 + j] = w2[idx];
    }
    __syncthreads();
    const int tl = tid >> 6, j = tid & 63;
    const float frj = fr[j];
    const float b0j = b0[j], b1j = b1[j], b2j = b2[j];
    const float w00 = w0[j*3+0], w01 = w0[j*3+1], w02 = w0[j*3+2];
    const int t0 = blockIdx.x * 64;
    for (int r = 0; r < 16; ++r) {
        int t = t0 + r*4 + tl;
        float z0 = z[t*3+0], z1 = z[t*3+1], z2 = z[t*3+2];
        float h = sinf(frj * (b0j + z0*w00 + z1*w01 + z2*w02));
        hb[tl][j] = h;
        __syncthreads();
        float s = b1j;
#pragma unroll
        for (int m = 0; m < 64; ++m) s = fmaf(hb[tl][m], w1t[m*65 + j], s);
        __syncthreads();
        h = sinf(frj * s);
        hb[tl][j] = h;
        __syncthreads();
        s = b2j;
#pragma unroll
        for (int m = 0; m < 64; ++m) s = fmaf(hb[tl][m], w2t[m*65 + j], s);
        h = sinf(frj * s);
        H3[(size_t)t * 64 + j] = h;
        __syncthreads();
    }
}

// ---------------------------------------------------------------------------
// K3b: kf[d][t] = (H3 @ wf^T) * exp-decay
// ---------------------------------------------------------------------------
__global__ __launch_bounds__(256) void k_filt_k(
    const float* __restrict__ H3, const float* __restrict__ wf,
    float* __restrict__ kf)
{
    __shared__ float Hs[64][65];
    __shared__ float Ws[64][65];
    const int tid = threadIdx.x;
    const int t0 = blockIdx.x * 64, d0 = blockIdx.y * 64;
    for (int idx = tid; idx < 4096; idx += 256) {
        int r = idx >> 6, cc = idx & 63;
        Hs[r][cc] = H3[(size_t)(t0 + r) * 64 + cc];
        Ws[r][cc] = wf[(size_t)(d0 + r) * 64 + cc];
    }
    __syncthreads();
    const int tx = tid & 15, ty = tid >> 4;
    float acc[4][4];
#pragma unroll
    for (int i = 0; i < 4; ++i)
#pragma unroll
        for (int jj = 0; jj < 4; ++jj) acc[i][jj] = 0.f;
#pragma unroll
    for (int j = 0; j < 64; ++j) {
        float wv[4], hv[4];
#pragma unroll
        for (int i = 0; i < 4; ++i) wv[i] = Ws[4*ty + i][j];
#pragma unroll
        for (int i = 0; i < 4; ++i) hv[i] = Hs[4*tx + i][j];
#pragma unroll
        for (int i = 0; i < 4; ++i)
#pragma unroll
            for (int jj = 0; jj < 4; ++jj) acc[i][jj] = fmaf(wv[i], hv[jj], acc[i][jj]);
    }
    const float mind = -3.0701134573253944f;
    const float maxd = -15.350567286626972f;
#pragma unroll
    for (int i = 0; i < 4; ++i) {
        int d = d0 + 4*ty + i;
        float delta = fabsf(mind + (maxd - mind) * ((float)d / 1023.f));
#pragma unroll
        for (int jj = 0; jj < 4; ++jj) {
            int t = t0 + 4*tx + jj;
            float tn = (float)t / 4095.f;
            kf[(size_t)d * LL + t] = acc[i][jj] * expf(-tn * delta);
        }
    }
}

// ---------------------------------------------------------------------------
// FFT helpers (8192-pt, radix-4 LDS stages; permutation identical to the
// radix-2 DIF/DIT chain). Fwd h=4096 fused into load; inv h=4096 fused
// into epilogue.
// ---------------------------------------------------------------------------
__device__ __forceinline__ int pidx(int p) { return p + (p >> 4); }

__device__ __forceinline__ float2 cmul(float2 a, float2 b) {
    return make_float2(a.x*b.x - a.y*b.y, a.x*b.y + a.y*b.x);
}

__device__ void fft_lds_fwd4(float2* buf, int tid) {
    int lh = 10;
#pragma unroll
    for (int h = 2048; h >= 32; h >>= 2, lh -= 2) {
        const int hh = h >> 1;
        const float rinv = -FPI / (float)h;
        __syncthreads();
#pragma unroll
        for (int r = 0; r < 4; ++r) {
            int bf = (r << 9) + tid;
            int q  = bf & (hh - 1);
            int g  = bf >> lh;
            int j  = (g << (lh + 2)) + q;
            float2 a = buf[pidx(j)];
            float2 b = buf[pidx(j + hh)];
            float2 c = buf[pidx(j + h)];
            float2 d = buf[pidx(j + h + hh)];
            float2 t0 = make_float2(a.x + c.x, a.y + c.y);
            float2 t1 = make_float2(a.x - c.x, a.y - c.y);
            float2 t2 = make_float2(b.x + d.x, b.y + d.y);
            float2 t3 = make_float2(b.y - d.y, d.x - b.x);
            float sn, cs;
            __sincosf(rinv * (float)q, &sn, &cs);
            float c2 = cs*cs - sn*sn, s2 = 2.f*cs*sn;
            float c3 = cs*c2 - sn*s2, s3 = cs*s2 + sn*c2;
            buf[pidx(j)] = make_float2(t0.x + t2.x, t0.y + t2.y);
            float2 e1 = make_float2(t0.x - t2.x, t0.y - t2.y);
            buf[pidx(j + hh)] = make_float2(e1.x*c2 - e1.y*s2, e1.x*s2 + e1.y*c2);
            float2 e2 = make_float2(t1.x + t3.x, t1.y + t3.y);
            buf[pidx(j + h)] = make_float2(e2.x*cs - e2.y*sn, e2.x*sn + e2.y*cs);
            float2 e3 = make_float2(t1.x - t3.x, t1.y - t3.y);
            buf[pidx(j + h + hh)] = make_float2(e3.x*c3 - e3.y*s3, e3.x*s3 + e3.y*c3);
        }
    }
    __syncthreads();
}

__device__ void fft_lds_inv4(float2* buf, int tid) {
    int lh = 4;
#pragma unroll
    for (int h = 32; h <= 2048; h <<= 2, lh += 2) {
        const int hh = h >> 1;
        const float rpos = FPI / (float)h;
        __syncthreads();
#pragma unroll
        for (int r = 0; r < 4; ++r) {
            int bf = (r << 9) + tid;
            int q  = bf & (hh - 1);
            int g  = bf >> lh;
            int j  = (g << (lh + 2)) + q;
            float2 o0 = buf[pidx(j)];
            float2 o1 = buf[pidx(j + hh)];
            float2 o2 = buf[pidx(j + h)];
            float2 o3 = buf[pidx(j + h + hh)];
            float sn, cs;
            __sincosf(rpos * (float)q, &sn, &cs);
            float c2 = cs*cs - sn*sn, s2 = 2.f*cs*sn;
            float c3 = cs*c2 - sn*s2, s3 = cs*s2 + sn*c2;
            float2 p1 = make_float2(o1.x*c2 - o1.y*s2, o1.x*s2 + o1.y*c2);
            float2 p2 = make_float2(o2.x*cs - o2.y*sn, o2.x*sn + o2.y*cs);
            float2 p3 = make_float2(o3.x*c3 - o3.y*s3, o3.x*s3 + o3.y*c3);
            float2 u0 = make_float2(o0.x + p1.x, o0.y + p1.y);
            float2 u1 = make_float2(o0.x - p1.x, o0.y - p1.y);
            float2 u2 = make_float2(p2.x + p3.x, p2.y + p3.y);
            float2 u3 = make_float2(p2.x - p3.x, p2.y - p3.y);
            float2 ib = make_float2(-u3.y, u3.x);
            buf[pidx(j)]          = make_float2(u0.x + u2.x, u0.y + u2.y);
            buf[pidx(j + hh)]     = make_float2(u1.x + ib.x, u1.y + ib.y);
            buf[pidx(j + h)]      = make_float2(u0.x - u2.x, u0.y - u2.y);
            buf[pidx(j + h + hh)] = make_float2(u1.x - ib.x, u1.y - ib.y);
        }
    }
    __syncthreads();
}

__device__ __forceinline__ void fft_reg_fwd(float2* c) {
    const float W16r[8] = {1.f, 0.92387953f, 0.70710678f, 0.38268343f,
                           0.f, -0.38268343f, -0.70710678f, -0.92387953f};
    const float W16i[8] = {0.f, -0.38268343f, -0.70710678f, -0.92387953f,
                           -1.f, -0.92387953f, -0.70710678f, -0.38268343f};
#pragma unroll
    for (int k = 0; k < 8; ++k) {
        float2 a = c[k], b = c[k+8];
        float2 d = make_float2(a.x - b.x, a.y - b.y);
        c[k]   = make_float2(a.x + b.x, a.y + b.y);
        c[k+8] = cmul(d, make_float2(W16r[k], W16i[k]));
    }
    const float W8r[4] = {1.f, 0.70710678f, 0.f, -0.70710678f};
    const float W8i[4] = {0.f, -0.70710678f, -1.f, -0.70710678f};
#pragma unroll
    for (int blk = 0; blk < 16; blk += 8)
#pragma unroll
        for (int k = 0; k < 4; ++k) {
            float2 a = c[blk+k], b = c[blk+k+4];
            float2 d = make_float2(a.x - b.x, a.y - b.y);
            c[blk+k]   = make_float2(a.x + b.x, a.y + b.y);
            c[blk+k+4] = cmul(d, make_float2(W8r[k], W8i[k]));
        }
#pragma unroll
    for (int blk = 0; blk < 16; blk += 4) {
        {   float2 a = c[blk], b = c[blk+2];
            c[blk]   = make_float2(a.x + b.x, a.y + b.y);
            c[blk+2] = make_float2(a.x - b.x, a.y - b.y); }
        {   float2 a = c[blk+1], b = c[blk+3];
            float2 d = make_float2(a.x - b.x, a.y - b.y);
            c[blk+1] = make_float2(a.x + b.x, a.y + b.y);
            c[blk+3] = make_float2(d.y, -d.x); }
    }
#pragma unroll
    for (int blk = 0; blk < 16; blk += 2) {
        float2 a = c[blk], b = c[blk+1];
        c[blk]   = make_float2(a.x + b.x, a.y + b.y);
        c[blk+1] = make_float2(a.x - b.x, a.y - b.y);
    }
}

__device__ __forceinline__ void fft_reg_inv(float2* c) {
#pragma unroll
    for (int blk = 0; blk < 16; blk += 2) {
        float2 a = c[blk], b = c[blk+1];
        c[blk]   = make_float2(a.x + b.x, a.y + b.y);
        c[blk+1] = make_float2(a.x - b.x, a.y - b.y);
    }
#pragma unroll
    for (int blk = 0; blk < 16; blk += 4) {
        {   float2 a = c[blk], b = c[blk+2];
            c[blk]   = make_float2(a.x + b.x, a.y + b.y);
            c[blk+2] = make_float2(a.x - b.x, a.y - b.y); }
        {   float2 a = c[blk+1], b = c[blk+3];
            float2 bt = make_float2(-c[blk+3].y, c[blk+3].x);
            c[blk+1] = make_float2(a.x + bt.x, a.y + bt.y);
            c[blk+3] = make_float2(a.x - bt.x, a.y - bt.y); }
    }
    const float W8r[4] = {1.f, 0.70710678f, 0.f, -0.70710678f};
    const float W8i[4] = {0.f, 0.70710678f, 1.f, 0.70710678f};
#pragma unroll
    for (int blk = 0; blk < 16; blk += 8)
#pragma unroll
        for (int k = 0; k < 4; ++k) {
            float2 a = c[blk+k], b = c[blk+k+4];
            float2 bt = cmul(b, make_float2(W8r[k], W8i[k]));
            c[blk+k]   = make_float2(a.x + bt.x, a.y + bt.y);
            c[blk+k+4] = make_float2(a.x - bt.x, a.y - bt.y);
        }
    const float W16r[8] = {1.f, 0.92387953f, 0.70710678f, 0.38268343f,
                           0.f, -0.38268343f, -0.70710678f, -0.92387953f};
    const float W16i[8] = {0.f, 0.38268343f, 0.70710678f, 0.92387953f,
                           1.f, 0.92387953f, 0.70710678f, 0.38268343f};
#pragma unroll
    for (int k = 0; k < 8; ++k) {
        float2 a = c[k], b = c[k+8];
        float2 bt = cmul(b, make_float2(W16r[k], W16i[k]));
        c[k]   = make_float2(a.x + bt.x, a.y + bt.y);
        c[k+8] = make_float2(a.x - bt.x, a.y - bt.y);
    }
}

// ---------------------------------------------------------------------------
// K4a: kernel spectrum -> fp16x2 (scrambled, pre-scaled by 1/8192)
// ---------------------------------------------------------------------------
__global__ __launch_bounds__(512) void k_kfft(
    const float* __restrict__ kf, f16x2* __restrict__ Kf)
{
    __shared__ float2 buf[8704];
    const int d = blockIdx.x, tid = threadIdx.x;
    const float* krow = kf + (size_t)d * LL;
    const float rinv0 = -FPI / 4096.f;
    for (int i = tid; i < 1024; i += 512) {
        float4 k4 = reinterpret_cast<const float4*>(krow)[i];
        int p = 4 * i;
        float kv[4] = {k4.x, k4.y, k4.z, k4.w};
#pragma unroll
        for (int q = 0; q < 4; ++q) {
            float sn, cs;
            __sincosf(rinv0 * (float)(p + q), &sn, &cs);
            buf[pidx(p + q)]        = make_float2(kv[q], 0.f);
            buf[pidx(p + q + 4096)] = make_float2(kv[q] * cs, kv[q] * sn);
        }
    }
    fft_lds_fwd4(buf, tid);
    float2 c[16];
    const int p0 = tid * 16;
#pragma unroll
    for (int j = 0; j < 16; ++j) c[j] = buf[pidx(p0 + j)];
    fft_reg_fwd(c);
    f16x2* outp = Kf + (size_t)d * 8192 + p0;
#pragma unroll
    for (int j = 0; j < 16; ++j) {
        f16x2 o;
        o[0] = (_Float16)(c[j].x * (1.f/8192.f));
        o[1] = (_Float16)(c[j].y * (1.f/8192.f));
        outp[j] = o;
    }
}

// ---------------------------------------------------------------------------
// K4b: batch-folded fft conv (z = v0 + i*v1); final inverse h=4096 stage
// fused into epilogue; + D*v skip + x0 gate; bf16 out per batch.
// ---------------------------------------------------------------------------
__global__ __launch_bounds__(512) void k_fftconv(
    const float* __restrict__ vin, const f16x2* __restrict__ Kf,
    const float* __restrict__ x0t, const float* __restrict__ Dp,
    ushort* __restrict__ yg)
{
    __shared__ float2 buf[8704];
    const int d = blockIdx.x, tid = threadIdx.x;
    const float* vrow0 = vin + (size_t)d * LL;
    const float* vrow1 = vin + ((size_t)DM + d) * LL;
    const float rinv0 = -FPI / 4096.f;
    for (int i = tid; i < 1024; i += 512) {
        float4 a4 = reinterpret_cast<const float4*>(vrow0)[i];
        float4 b4 = reinterpret_cast<const float4*>(vrow1)[i];
        int p = 4 * i;
        float ar[4] = {a4.x, a4.y, a4.z, a4.w};
        float br[4] = {b4.x, b4.y, b4.z, b4.w};
#pragma unroll
        for (int q = 0; q < 4; ++q) {
            float sn, cs;
            __sincosf(rinv0 * (float)(p + q), &sn, &cs);
            float2 z = make_float2(ar[q], br[q]);
            buf[pidx(p + q)]        = z;
            buf[pidx(p + q + 4096)] = cmul(z, make_float2(cs, sn));
        }
    }
    fft_lds_fwd4(buf, tid);
    float2 c[16];
    const int p0 = tid * 16;
#pragma unroll
    for (int j = 0; j < 16; ++j) c[j] = buf[pidx(p0 + j)];
    fft_reg_fwd(c);
    const f16x2* kfr = Kf + (size_t)d * 8192 + p0;
#pragma unroll
    for (int j = 0; j < 16; ++j) {
        f16x2 kv = kfr[j];
        c[j] = cmul(c[j], make_float2((float)kv[0], (float)kv[1]));
    }
    fft_reg_inv(c);
#pragma unroll
    for (int j = 0; j < 16; ++j) buf[pidx(p0 + j)] = c[j];
    fft_lds_inv4(buf, tid);
    const float Dd = Dp[d];
    const float* xrow0 = x0t + (size_t)d * LL;
    const float* xrow1 = x0t + ((size_t)DM + d) * LL;
    ushort* orow0 = yg + (size_t)d * LL;
    ushort* orow1 = yg + ((size_t)DM + d) * LL;
    const float rinv4 = FPI / 4096.f;
    for (int i = tid; i < 1024; i += 512) {
        float4 v0 = reinterpret_cast<const float4*>(vrow0)[i];
        float4 v1 = reinterpret_cast<const float4*>(vrow1)[i];
        float4 x0 = reinterpret_cast<const float4*>(xrow0)[i];
        float4 x1 = reinterpret_cast<const float4*>(xrow1)[i];
        int p = 4 * i;
        float vr0[4] = {v0.x, v0.y, v0.z, v0.w};
        float vr1[4] = {v1.x, v1.y, v1.z, v1.w};
        float xr0[4] = {x0.x, x0.y, x0.z, x0.w};
        float xr1[4] = {x1.x, x1.y, x1.z, x1.w};
        ushort s0[4], s1[4];
#pragma unroll
        for (int q = 0; q < 4; ++q) {
            float sn, cs;
            __sincosf(rinv4 * (float)(p + q), &sn, &cs);
            float2 a  = buf[pidx(p + q)];
            float2 bb = buf[pidx(p + q + 4096)];
            float2 bt = cmul(bb, make_float2(cs, sn));
            float yre = a.x + bt.x;
            float yim = a.y + bt.y;
            s0[q] = f2bf((yre + Dd * vr0[q]) * xr0[q]);
            s1[q] = f2bf((yim + Dd * vr1[q]) * xr1[q]);
        }
        *reinterpret_cast<ushort4*>(orow0 + p) = make_ushort4(s0[0], s0[1], s0[2], s0[3]);
        *reinterpret_cast<ushort4*>(orow1 + p) = make_ushort4(s1[0], s1[1], s1[2], s1[3]);
    }
}

// ---------------------------------------------------------------------------
// K_tr: yg[b][d][t] (bf16) -> Ag[b][t][d] (bf16), 64x64 LDS tiles
// ---------------------------------------------------------------------------
__global__ __launch_bounds__(256) void k_tr(
    const ushort* __restrict__ yg, ushort* __restrict__ Ag)
{
    __shared__ ushort S[64][72];
    const int b  = blockIdx.z;
    const int d0 = blockIdx.y * 64;
    const int t0 = blockIdx.x * 64;
    const int tid = threadIdx.x;
#pragma unroll
    for (int p = 0; p < 2; ++p) {
        int idx = p * 256 + tid;
        int dr = idx >> 3, c8 = (idx & 7) << 3;
        uint4 v = *reinterpret_cast<const uint4*>(
            yg + ((size_t)b * DM + d0 + dr) * LL + t0 + c8);
        *reinterpret_cast<uint4*>(&S[dr][c8]) = v;
    }
    __syncthreads();
#pragma unroll
    for (int p = 0; p < 2; ++p) {
        int idx = p * 256 + tid;
        int tr = idx >> 3, dq = (idx & 7) << 3;
        ushort tmp[8] __attribute__((aligned(16)));
#pragma unroll
        for (int q = 0; q < 8; ++q) tmp[q] = S[dq + q][tr];
        *reinterpret_cast<uint4*>(Ag + ((size_t)b * LL + t0 + tr) * DM + d0 + dq) =
            *reinterpret_cast<uint4*>(tmp);
    }
}

// ---------------------------------------------------------------------------
extern "C" void kernel_launch(void* const* d_in, const int* in_sizes, int n_in,
                              void* d_out, int out_size, void* d_ws, size_t ws_size,
                              hipStream_t stream)
{
    if (n_in < 17) return;
    const float* u    = (const float*)d_in[0];
    const float* w_in = (const float*)d_in[1];
    const float* b_in = (const float*)d_in[2];
    const float* sf_w = (const float*)d_in[3];
    const float* sf_b = (const float*)d_in[4];
    const float* z    = (const float*)d_in[5];
    const float* w0   = (const float*)d_in[6];
    const float* b0   = (const float*)d_in[7];
    const float* freq = (const float*)d_in[8];
    const float* w1   = (const float*)d_in[9];
    const float* b1   = (const float*)d_in[10];
    const float* w2   = (const float*)d_in[11];
    const float* b2   = (const float*)d_in[12];
    const float* wf   = (const float*)d_in[13];
    const float* Dp   = (const float*)d_in[14];
    const float* wout = (const float*)d_in[15];
    const float* bout = (const float*)d_in[16];
    float* out = (float*)d_out;
    float* ws  = (float*)d_ws;

    // Overlaid workspace (float offsets) — same layout as round 3/4.
    // Kf now fp16x2 (4B/bin): occupies [0, 8388608) floats, within old slot.
    float*  up    = ws;
    f16x2*  Kf    = (f16x2*)ws;
    float*  kfbuf = ws + 16777216;
    ushort* yg    = (ushort*)(ws + 16777216);
    float*  H3    = ws + 20971520;
    ushort* Ag    = (ushort*)(ws + 20971520);
    ushort* ub    = (ushort*)(ws + 25165824);
    float*  x0t   = ws + 25165824;
    ushort* wb    = (ushort*)(ws + 33554432);
    float*  vin   = ws + 33554432;
    ushort* woutb = (ushort*)(ws + 33554432);
    const size_t NEED = (size_t)41943040 * 4;
    if (ws_size < NEED) return;

    hipLaunchKernelGGL(k_cvt_bf16, dim3(2048), dim3(256), 0, stream, u, ub, 2097152);
    hipLaunchKernelGGL(k_cvt_bf16, dim3(2048), dim3(256), 0, stream, w_in, wb, 786432);
    // up = u @ w_in^T + b_in : 256^2 8-phase MFMA (384 blocks, %8==0)
    hipLaunchKernelGGL(k_gemm256, dim3((8192/256) * (E3/256)), dim3(512), 0, stream,
                       ub, wb, b_in, up, E3/256, E3);
    hipLaunchKernelGGL(k_dwconv,   dim3(DM/32, LL/64, NB), dim3(256), 0, stream,
                       up, sf_w, sf_b, x0t, vin);
    hipLaunchKernelGGL(k_filt_mlp, dim3(LL/64), dim3(256), 0, stream,
                       z, w0, b0, freq, w1, b1, w2, b2, H3);
    hipLaunchKernelGGL(k_filt_k,   dim3(LL/64, DM/64), dim3(256), 0, stream,
                       H3, wf, kfbuf);
    hipLaunchKernelGGL(k_kfft,     dim3(DM), dim3(512), 0, stream,
                       kfbuf, Kf);
    hipLaunchKernelGGL(k_fftconv,  dim3(DM), dim3(512), 0, stream,
                       vin, Kf, x0t, Dp, yg);
    hipLaunchKernelGGL(k_cvt_bf16, dim3(1024), dim3(256), 0, stream, wout, woutb, 262144);
    hipLaunchKernelGGL(k_tr,       dim3(LL/64, DM/64, NB), dim3(256), 0, stream,
                       yg, Ag);
    hipLaunchKernelGGL(k_gemm_bf16, dim3(DM/128, 8192/128), dim3(256), 0, stream,
                       Ag, woutb, bout, out, DM);
}